// Round 6
// baseline (3212.296 us; speedup 1.0000x reference)
//
#include <hip/hip_runtime.h>

#define DEV __device__ __forceinline__

namespace {

constexpr int B_ = 8;
constexpr int N_ = 1024;
constexpr int M_ = 256;
constexpr int D_ = 25;
constexpr int FH_ = 240;
constexpr int NATOM = B_ * N_;          // 8192
constexpr float CSC = 1.0f / 256.0f;    // 4/(NN*NTYPES*4)
constexpr int GATOMS = 8;               // atoms per K3 block
constexpr int GROUPS = N_ / GATOMS;     // 128 groups per batch

DEV float fast_tanh(float x) {
  float ax = fabsf(x);
  float e = __expf(-2.0f * ax);
  float r = (1.0f - e) * __builtin_amdgcn_rcpf(1.0f + e);
  return copysignf(r, x);
}

// Scalar geometry pieces shared by descriptor and Jacobian.
struct Geom {
  float mf, inr, inr2, inr4, inr3, vv, dvv;
};

DEV Geom geom_core(float dx, float dy, float dz, int nb) {
  Geom g;
  g.mf = (nb > 0) ? 1.0f : 0.0f;
  float dr2 = dx * dx + dy * dy + dz * dz;
  float safe = (nb > 0) ? dr2 : 1.0f;
  float rs = __builtin_amdgcn_rsqf(safe);   // 1/sqrt(safe)
  float rij = safe * rs;                    // sqrt(safe)
  g.inr = g.mf * rs;
  float x = rij * g.mf;
  g.inr2 = g.inr * g.inr;
  g.inr4 = g.inr2 * g.inr2;
  g.inr3 = g.inr4 * x;
  float u = (x - 5.8f) * 5.0f;              // (x-RMIN)/(RMAX-RMIN)
  float uu = u * u;
  float A = -6.0f * uu + 15.0f * u - 10.0f;
  float poly = uu * u * A + 1.0f;
  float dpoly = (3.0f * uu * A + uu * u * (-12.0f * u + 15.0f)) * 5.0f;
  bool mid = (x >= 5.8f) && (x < 6.0f);
  g.vv = ((x < 5.8f) ? 1.0f : (mid ? poly : 0.0f)) * g.mf;
  g.dvv = (mid ? dpoly : 0.0f) * g.mf;
  return g;
}

// Normalized descriptor channels blk[4]; also returns 1/dstd per channel.
DEV void geom_blk(const Geom& g, float dx, float dy, float dz, int t, int m,
                  const float* __restrict__ davg, const float* __restrict__ dstd,
                  float* __restrict__ blk, float* __restrict__ rsv) {
  int bidx = (t * M_ + m) * 4;
  float4 av = *(const float4*)(davg + bidx);
  float4 sv = *(const float4*)(dstd + bidx);
  float pre[4] = {g.inr, dx * g.inr2, dy * g.inr2, dz * g.inr2};
  float avf[4] = {av.x, av.y, av.z, av.w};
  float svf[4] = {sv.x, sv.y, sv.z, sv.w};
#pragma unroll
  for (int d = 0; d < 4; ++d) {
    rsv[d] = __builtin_amdgcn_rcpf(svf[d]);
    blk[d] = (pre[d] * g.vv - avf[d]) * rsv[d];
  }
}

// K1: per atom (block), per neighbor (thread): geometry + lean embedding fwd,
// then acc[4][25] = CSC * sum_m blk[m][d] * G[m][e] via LDS reduction.
__global__ __launch_bounds__(256) void k_embed_acc(
    const float* __restrict__ dR, const int* __restrict__ neigh,
    const float* __restrict__ davg, const float* __restrict__ dstd,
    const float* __restrict__ eW0, const float* __restrict__ eb0,
    const float* __restrict__ eW1, const float* __restrict__ eb1,
    const float* __restrict__ eW2, const float* __restrict__ eb2,
    float* __restrict__ acc_ws) {
  __shared__ float sG[M_ * D_];
  __shared__ float4 sBlk[M_];
  int atom = blockIdx.x;
  int n = atom & (N_ - 1);
  int t = (n >= 512) ? 1 : 0;
  int m = threadIdx.x;
  // pair index is uniform across each 64-lane wave (m>>7 constant per wave)
  int p = __builtin_amdgcn_readfirstlane(t * 2 + (m >> 7));
  const float* W0 = eW0 + p * D_;
  const float* b0 = eb0 + p * D_;
  const float* W1 = eW1 + p * D_ * D_;
  const float* b1 = eb1 + p * D_;
  const float* W2 = eW2 + p * D_ * D_;
  const float* b2 = eb2 + p * D_;
  int base = atom * M_ + m;
  float dx = dR[base * 3 + 0];
  float dy = dR[base * 3 + 1];
  float dz = dR[base * 3 + 2];
  int nb = neigh[base];
  Geom g = geom_core(dx, dy, dz, nb);
  float blk[4], rsv[4];
  geom_blk(g, dx, dy, dz, t, m, davg, dstd, blk, rsv);
  float s = blk[0];
  float h[D_], a[D_];
#pragma unroll
  for (int e = 0; e < D_; ++e) h[e] = fast_tanh(fmaf(s, W0[e], b0[e]));
#pragma unroll
  for (int e = 0; e < D_; ++e) a[e] = b1[e];
#pragma unroll
  for (int f = 0; f < D_; ++f) {
    float hf = h[f];
#pragma unroll
    for (int e = 0; e < D_; ++e) a[e] = fmaf(hf, W1[f * D_ + e], a[e]);
  }
#pragma unroll
  for (int e = 0; e < D_; ++e) h[e] += fast_tanh(a[e]);   // h1
#pragma unroll
  for (int e = 0; e < D_; ++e) a[e] = b2[e];
#pragma unroll
  for (int f = 0; f < D_; ++f) {
    float hf = h[f];
#pragma unroll
    for (int e = 0; e < D_; ++e) a[e] = fmaf(hf, W2[f * D_ + e], a[e]);
  }
#pragma unroll
  for (int e = 0; e < D_; ++e) sG[m * D_ + e] = h[e] + fast_tanh(a[e]);  // G
  sBlk[m] = make_float4(blk[0], blk[1], blk[2], blk[3]);
  __syncthreads();
  if (threadIdx.x < 100) {
    int d = threadIdx.x & 3;
    int e = threadIdx.x >> 2;
    const float* sb = (const float*)sBlk;
    // 4-way partial sums: break the serial fma/ds_read dependence chain
    float s0 = 0.0f, s1 = 0.0f, s2 = 0.0f, s3 = 0.0f;
    for (int mm = 0; mm < M_; mm += 4) {
      s0 = fmaf(sb[(mm + 0) * 4 + d], sG[(mm + 0) * D_ + e], s0);
      s1 = fmaf(sb[(mm + 1) * 4 + d], sG[(mm + 1) * D_ + e], s1);
      s2 = fmaf(sb[(mm + 2) * 4 + d], sG[(mm + 2) * D_ + e], s2);
      s3 = fmaf(sb[(mm + 3) * 4 + d], sG[(mm + 3) * D_ + e], s3);
    }
    acc_ws[atom * 100 + d * D_ + e] = ((s0 + s1) + (s2 + s3)) * CSC;
  }
}

// K2: 8 atoms per block. DRt + fitting net fwd + bwd, emits Ei/Etot and dacc.
__global__ __launch_bounds__(256) void k_fit(
    const float* __restrict__ acc_ws,
    const float* __restrict__ fW0, const float* __restrict__ fb0,
    const float* __restrict__ fW1, const float* __restrict__ fb1,
    const float* __restrict__ fW2, const float* __restrict__ fb2,
    const float* __restrict__ fW3, const float* __restrict__ fb3,
    const float* __restrict__ ener_shift,
    float* __restrict__ dacc_ws, float* __restrict__ out) {
  constexpr int AB = 8;
  __shared__ float sAcc[AB][100];
  __shared__ float sX[AB][400];   // x fwd, then dx bwd
  __shared__ float sH0[AB][FH_];  // h0, then g0
  __shared__ float sT1[AB][FH_];  // tanh1, then g1
  __shared__ float sH1[AB][FH_];  // h1, then dh1
  __shared__ float sT2[AB][FH_];  // tanh2, then g2
  __shared__ float sEi[AB];
  int a0 = blockIdx.x * AB;
  int bb = a0 >> 10;
  int n0 = a0 & (N_ - 1);
  int t = (n0 >= 512) ? 1 : 0;
  int tid = threadIdx.x;
  for (int idx = tid; idx < AB * 100; idx += 256)
    ((float*)sAcc)[idx] = acc_ws[a0 * 100 + idx];
  if (tid < AB) sEi[tid] = 0.0f;
  __syncthreads();
  // DRt[e][f] = sum_d acc[d][e]*acc[d][f], f<16
  for (int idx = tid; idx < AB * 400; idx += 256) {
    int a = idx / 400; int r = idx % 400; int e = r >> 4; int f = r & 15;
    const float* A = sAcc[a];
    sX[a][r] = A[e] * A[f] + A[25 + e] * A[25 + f] + A[50 + e] * A[50 + f] +
               A[75 + e] * A[75 + f];
  }
  __syncthreads();
  const float* W0 = fW0 + t * 400 * FH_;
  const float* W1 = fW1 + t * FH_ * FH_;
  const float* W2 = fW2 + t * FH_ * FH_;
  const float* B0 = fb0 + t * FH_;
  const float* B1 = fb1 + t * FH_;
  const float* B2 = fb2 + t * FH_;
  const float* W3 = fW3 + t * FH_;
  int j = tid;
  if (j < FH_) {  // layer 0: 400 -> 240
    float acc8[AB];
#pragma unroll
    for (int a = 0; a < AB; ++a) acc8[a] = B0[j];
    for (int i = 0; i < 400; ++i) {
      float w = W0[i * FH_ + j];
#pragma unroll
      for (int a = 0; a < AB; ++a) acc8[a] = fmaf(sX[a][i], w, acc8[a]);
    }
#pragma unroll
    for (int a = 0; a < AB; ++a) sH0[a][j] = fast_tanh(acc8[a]);
  }
  __syncthreads();
  if (j < FH_) {  // layer 1 (residual)
    float acc8[AB];
#pragma unroll
    for (int a = 0; a < AB; ++a) acc8[a] = B1[j];
    for (int f = 0; f < FH_; ++f) {
      float w = W1[f * FH_ + j];
#pragma unroll
      for (int a = 0; a < AB; ++a) acc8[a] = fmaf(sH0[a][f], w, acc8[a]);
    }
#pragma unroll
    for (int a = 0; a < AB; ++a) {
      float tv = fast_tanh(acc8[a]);
      sT1[a][j] = tv;
      sH1[a][j] = sH0[a][j] + tv;
    }
  }
  __syncthreads();
  if (j < FH_) {  // layer 2 (residual) + Ei dot
    float acc8[AB];
#pragma unroll
    for (int a = 0; a < AB; ++a) acc8[a] = B2[j];
    for (int f = 0; f < FH_; ++f) {
      float w = W2[f * FH_ + j];
#pragma unroll
      for (int a = 0; a < AB; ++a) acc8[a] = fmaf(sH1[a][f], w, acc8[a]);
    }
    float w3 = W3[j];
#pragma unroll
    for (int a = 0; a < AB; ++a) {
      float tv = fast_tanh(acc8[a]);
      sT2[a][j] = tv;
      atomicAdd(&sEi[a], (sH1[a][j] + tv) * w3);
    }
  }
  __syncthreads();
  if (tid < AB) {
    float ei = sEi[tid] + fb3[t] + ener_shift[t];
    out[8 + a0 + tid] = ei;            // Ei
    atomicAdd(&out[bb], ei);           // Etot
  }
  if (j < FH_) {  // g2 = W3 * (1 - t2^2)   (dEi = 1)
    float w3 = W3[j];
#pragma unroll
    for (int a = 0; a < AB; ++a) {
      float tv = sT2[a][j];
      sT2[a][j] = w3 * (1.0f - tv * tv);
    }
  }
  __syncthreads();
  if (j < FH_) {  // dh1 = W3 + g2 @ W2^T ; g1 = dh1*(1-t1^2)
    float w3 = W3[j];
    float acc8[AB];
#pragma unroll
    for (int a = 0; a < AB; ++a) acc8[a] = w3;
    for (int k = 0; k < FH_; ++k) {
      float w = W2[j * FH_ + k];
#pragma unroll
      for (int a = 0; a < AB; ++a) acc8[a] = fmaf(sT2[a][k], w, acc8[a]);
    }
#pragma unroll
    for (int a = 0; a < AB; ++a) {
      float dh1 = acc8[a];
      float tv = sT1[a][j];
      sH1[a][j] = dh1;
      sT1[a][j] = dh1 * (1.0f - tv * tv);
    }
  }
  __syncthreads();
  if (j < FH_) {  // dh0 = dh1 + g1 @ W1^T ; g0 = dh0*(1-h0^2)
    float acc8[AB];
#pragma unroll
    for (int a = 0; a < AB; ++a) acc8[a] = sH1[a][j];
    for (int k = 0; k < FH_; ++k) {
      float w = W1[j * FH_ + k];
#pragma unroll
      for (int a = 0; a < AB; ++a) acc8[a] = fmaf(sT1[a][k], w, acc8[a]);
    }
#pragma unroll
    for (int a = 0; a < AB; ++a) {
      float h0v = sH0[a][j];
      sH0[a][j] = acc8[a] * (1.0f - h0v * h0v);
    }
  }
  __syncthreads();
  // dx = g0 @ W0^T  (overwrite sX)
  for (int i = tid; i < 400; i += 256) {
    float acc8[AB];
#pragma unroll
    for (int a = 0; a < AB; ++a) acc8[a] = 0.0f;
    for (int jj = 0; jj < FH_; ++jj) {
      float w = W0[i * FH_ + jj];
#pragma unroll
      for (int a = 0; a < AB; ++a) acc8[a] = fmaf(sH0[a][jj], w, acc8[a]);
    }
#pragma unroll
    for (int a = 0; a < AB; ++a) sX[a][i] = acc8[a];
  }
  __syncthreads();
  // dacc[d][e] = sum_{f<16} dDRt[e][f]*acc[d][f] + [e<16] sum_e2 dDRt[e2][e]*acc[d][e2]
  for (int idx = tid; idx < AB * 100; idx += 256) {
    int a = idx / 100; int r = idx % 100; int d = r / 25; int e = r % 25;
    const float* A = sAcc[a];
    const float* DX = sX[a];
    float sum = 0.0f;
#pragma unroll
    for (int f = 0; f < 16; ++f) sum = fmaf(DX[e * 16 + f], A[d * 25 + f], sum);
    if (e < 16) {
#pragma unroll
      for (int e2 = 0; e2 < 25; ++e2) sum = fmaf(DX[e2 * 16 + e], A[d * 25 + e2], sum);
    }
    dacc_ws[a0 * 100 + idx] = sum;
  }
}

// K3: R5 post-mortem: atomic elimination worked (WRITE 518->6MB) but dur
// stayed 572us: grid was 512 blocks = 2 blocks/CU (grid-capped), so each
// SIMD held ~2 waves; dependent FMA chains + s_load waits + quarter-rate
// tanh left VALUBusy at 68% with nothing to fill the gaps (Occupancy 11.8%).
// Fix: GATOMS 16->8 (grid 1024 = 4 blocks/CU; LDS 37.6KB allows exactly 4)
// + launch_bounds(256,4) caps the allocator at 128 VGPR (R5 chose 144; the
// ~16 over-budget temps are loop-invariant hoists, rematerializable).
// LDS caps waves/SIMD at 4 anyway, so the allocator cannot chase a 6-wave
// spill regime (R1 lesson).
__global__ __launch_bounds__(256, 4) void k_bwd_force(
    const float* __restrict__ dR, const int* __restrict__ neigh,
    const float* __restrict__ davg, const float* __restrict__ dstd,
    const float* __restrict__ eW0, const float* __restrict__ eb0,
    const float* __restrict__ eW1, const float* __restrict__ eb1,
    const float* __restrict__ eW2, const float* __restrict__ eb2,
    const float* __restrict__ dacc_ws, float* __restrict__ partials) {
  __shared__ float sHP[D_][256];   // dh/ds column per thread (25.6KB)
  __shared__ float sF[N_ * 3];     // per-batch force bins (12KB)
  int bg = blockIdx.x;
  int b = bg / GROUPS;
  int grp = bg - b * GROUPS;
  int n0 = grp * GATOMS;           // 8 | 512 -> t uniform per block
  int t = (n0 >= 512) ? 1 : 0;
  int m = threadIdx.x;
  for (int i = m; i < N_ * 3; i += 256) sF[i] = 0.0f;
  int p = __builtin_amdgcn_readfirstlane(t * 2 + (m >> 7));
  const float* W0 = eW0 + p * D_;
  const float* b0 = eb0 + p * D_;
  const float* W1 = eW1 + p * D_ * D_;
  const float* b1 = eb1 + p * D_;
  const float* W2 = eW2 + p * D_ * D_;
  const float* b2 = eb2 + p * D_;
  __syncthreads();

#pragma unroll 1
  for (int k = 0; k < GATOMS; ++k) {
    int n = n0 + k;
    int atom = b * N_ + n;
    const float* dac = dacc_ws + atom * 100;  // block-uniform -> scalar loads
    int base = atom * M_ + m;
    float dx = dR[base * 3 + 0];
    float dy = dR[base * 3 + 1];
    float dz = dR[base * 3 + 2];
    int nb = neigh[base];
    Geom g = geom_core(dx, dy, dz, nb);
    float blk[4], rsv[4];
    geom_blk(g, dx, dy, dz, t, m, davg, dstd, blk, rsv);
    float s = blk[0];

    // ---- layer 0: h in regs, hp -> LDS column ----
    float h[D_];
#pragma unroll
    for (int e = 0; e < D_; ++e) {
      float th = fast_tanh(fmaf(s, W0[e], b0[e]));
      h[e] = th;
      sHP[e][m] = (1.0f - th * th) * W0[e];
    }
    // ---- layer 1 (residual) ----
    {
      float a[D_], ap[D_];
#pragma unroll
      for (int e = 0; e < D_; ++e) { a[e] = b1[e]; ap[e] = 0.0f; }
#pragma unroll
      for (int f = 0; f < D_; ++f) {
        float hf = h[f];
        float hpf = sHP[f][m];
#pragma unroll
        for (int e = 0; e < D_; ++e) {
          float w = W1[f * D_ + e];
          a[e] = fmaf(hf, w, a[e]);
          ap[e] = fmaf(hpf, w, ap[e]);
        }
      }
#pragma unroll
      for (int e = 0; e < D_; ++e) {
        float th = fast_tanh(a[e]);
        sHP[e][m] = fmaf(1.0f - th * th, ap[e], sHP[e][m]);
        h[e] += th;
      }
    }
    // ---- layer 2 (residual): outputs folded e-by-e into 5 scalars ----
    float ds = 0.0f, db0 = 0.0f, db1 = 0.0f, db2 = 0.0f, db3 = 0.0f;
    {
      float a[D_], ap[D_];
#pragma unroll
      for (int e = 0; e < D_; ++e) { a[e] = b2[e]; ap[e] = 0.0f; }
#pragma unroll
      for (int f = 0; f < D_; ++f) {
        float hf = h[f];
        float hpf = sHP[f][m];
#pragma unroll
        for (int e = 0; e < D_; ++e) {
          float w = W2[f * D_ + e];
          a[e] = fmaf(hf, w, a[e]);
          ap[e] = fmaf(hpf, w, ap[e]);
        }
      }
#pragma unroll
      for (int e = 0; e < D_; ++e) {
        float th = fast_tanh(a[e]);
        float G = h[e] + th;                               // final G[e]
        float hp2 = fmaf(1.0f - th * th, ap[e], sHP[e][m]);// dG[e]/ds
        float d0 = dac[e], d1 = dac[25 + e], d2 = dac[50 + e], d3 = dac[75 + e];
        float u = d0 * blk[0] + d1 * blk[1] + d2 * blk[2] + d3 * blk[3];
        ds = fmaf(u, hp2, ds);
        db0 = fmaf(d0, G, db0);
        db1 = fmaf(d1, G, db1);
        db2 = fmaf(d2, G, db2);
        db3 = fmaf(d3, G, db3);
      }
    }
    float dE0 = (db0 + ds) * CSC;
    float dE1 = db1 * CSC, dE2 = db2 * CSC, dE3 = db3 * CSC;

    // ---- fold the 4x3 geometry Jacobian directly into the force vector ----
    float dv[3] = {dx, dy, dz};
    float pre1[3] = {dx * g.inr2, dy * g.inr2, dz * g.inr2};
    float ci = g.dvv * g.inr;
    float com[3];
#pragma unroll
    for (int c = 0; c < 3; ++c) com[c] = ci * dv[c];
    float iv = g.inr3 * g.vv;
    float pc[3];
    float f0 = dE0 * rsv[0];
#pragma unroll
    for (int c = 0; c < 3; ++c) pc[c] = f0 * (dv[c] * iv - g.inr * com[c]);
    float dEr[3] = {dE1, dE2, dE3};
#pragma unroll
    for (int r = 0; r < 3; ++r) {
      float fr = dEr[r] * rsv[1 + r];
#pragma unroll
      for (int c = 0; c < 3; ++c) {
        float outer = 2.0f * dv[r] * dv[c] * g.inr4 - ((r == c) ? g.inr2 : 0.0f);
        pc[c] = fmaf(fr, outer * g.vv - pre1[r] * com[c], pc[c]);
      }
    }
    float px = pc[0] * g.mf, py = pc[1] * g.mf, pz = pc[2] * g.mf;

    if (nb > 0) {  // scatter to neighbor j = nb-1 (LDS bins, banked atomics)
      int jn = nb - 1;
      atomicAdd(&sF[jn * 3 + 0], px);
      atomicAdd(&sF[jn * 3 + 1], py);
      atomicAdd(&sF[jn * 3 + 2], pz);
    }
    // F_self: 64-lane shuffle reduce, one LDS atomic per wave per component
#pragma unroll
    for (int i = 1; i < 64; i <<= 1) {
      px += __shfl_xor(px, i);
      py += __shfl_xor(py, i);
      pz += __shfl_xor(pz, i);
    }
    if ((m & 63) == 0) {
      atomicAdd(&sF[n * 3 + 0], -px);
      atomicAdd(&sF[n * 3 + 1], -py);
      atomicAdd(&sF[n * 3 + 2], -pz);
    }
  }
  __syncthreads();
  // flush: plain coalesced stores (full overwrite, no zero-init needed)
  float* pb = partials + (size_t)bg * (N_ * 3);
  for (int i = m; i < N_ * 3; i += 256) pb[i] = sF[i];
}

// K4: F[b,j,c] = sum over group-partials. Zero atomics.
__global__ __launch_bounds__(256) void k_freduce(
    const float* __restrict__ partials, float* __restrict__ out) {
  int idx = blockIdx.x * 256 + threadIdx.x;   // < 8*3072
  int b = idx / (N_ * 3);
  int r = idx - b * (N_ * 3);
  const float* pp = partials + (size_t)(b * GROUPS) * (N_ * 3) + r;
  float s0 = 0.0f, s1 = 0.0f, s2 = 0.0f, s3 = 0.0f;
  for (int g = 0; g < GROUPS; g += 4) {
    s0 += pp[(g + 0) * (N_ * 3)];
    s1 += pp[(g + 1) * (N_ * 3)];
    s2 += pp[(g + 2) * (N_ * 3)];
    s3 += pp[(g + 3) * (N_ * 3)];
  }
  out[8 + NATOM + idx] = (s0 + s1) + (s2 + s3);
}

}  // namespace

extern "C" void kernel_launch(void* const* d_in, const int* in_sizes, int n_in,
                              void* d_out, int out_size, void* d_ws, size_t ws_size,
                              hipStream_t stream) {
  (void)in_sizes; (void)n_in; (void)ws_size;
  const float* image_dR   = (const float*)d_in[0];
  const int*   list_neigh = (const int*)d_in[1];
  const float* davg       = (const float*)d_in[2];
  const float* dstd       = (const float*)d_in[3];
  const float* eW0        = (const float*)d_in[4];
  const float* eb0        = (const float*)d_in[5];
  const float* eW1        = (const float*)d_in[6];
  const float* eb1        = (const float*)d_in[7];
  const float* eW2        = (const float*)d_in[8];
  const float* eb2        = (const float*)d_in[9];
  const float* fW0        = (const float*)d_in[10];
  const float* fb0        = (const float*)d_in[11];
  const float* fW1        = (const float*)d_in[12];
  const float* fb1        = (const float*)d_in[13];
  const float* fW2        = (const float*)d_in[14];
  const float* fb2        = (const float*)d_in[15];
  const float* fW3        = (const float*)d_in[16];
  const float* fb3        = (const float*)d_in[17];
  const float* ener_shift = (const float*)d_in[18];
  float* out = (float*)d_out;
  float* acc_ws   = (float*)d_ws;                   // 8192*100 floats
  float* dacc_ws  = acc_ws + NATOM * 100;           // 8192*100 floats
  float* partials = dacc_ws + NATOM * 100;          // 1024*3072 floats (12.6MB)

  hipMemsetAsync(d_out, 0, (size_t)out_size * sizeof(float), stream);
  k_embed_acc<<<NATOM, 256, 0, stream>>>(image_dR, list_neigh, davg, dstd,
                                         eW0, eb0, eW1, eb1, eW2, eb2, acc_ws);
  k_fit<<<NATOM / 8, 256, 0, stream>>>(acc_ws, fW0, fb0, fW1, fb1, fW2, fb2,
                                       fW3, fb3, ener_shift, dacc_ws, out);
  k_bwd_force<<<B_ * GROUPS, 256, 0, stream>>>(image_dR, list_neigh, davg, dstd,
                                               eW0, eb0, eW1, eb1, eW2, eb2,
                                               dacc_ws, partials);
  k_freduce<<<(B_ * N_ * 3) / 256, 256, 0, stream>>>(partials, out);
}

// Round 7
// 1874.626 us; speedup vs baseline: 1.7136x; 1.7136x over previous
//
#include <hip/hip_runtime.h>

#define DEV __device__ __forceinline__

namespace {

constexpr int B_ = 8;
constexpr int N_ = 1024;
constexpr int M_ = 256;
constexpr int D_ = 25;
constexpr int FH_ = 240;
constexpr int NATOM = B_ * N_;          // 8192
constexpr float CSC = 1.0f / 256.0f;    // 4/(NN*NTYPES*4)

DEV float fast_tanh(float x) {
  float ax = fabsf(x);
  float e = __expf(-2.0f * ax);
  float r = (1.0f - e) * __builtin_amdgcn_rcpf(1.0f + e);
  return copysignf(r, x);
}

// Scalar geometry pieces shared by descriptor and Jacobian.
struct Geom {
  float mf, inr, inr2, inr4, inr3, vv, dvv;
};

DEV Geom geom_core(float dx, float dy, float dz, int nb) {
  Geom g;
  g.mf = (nb > 0) ? 1.0f : 0.0f;
  float dr2 = dx * dx + dy * dy + dz * dz;
  float safe = (nb > 0) ? dr2 : 1.0f;
  float rs = __builtin_amdgcn_rsqf(safe);   // 1/sqrt(safe)
  float rij = safe * rs;                    // sqrt(safe)
  g.inr = g.mf * rs;
  float x = rij * g.mf;
  g.inr2 = g.inr * g.inr;
  g.inr4 = g.inr2 * g.inr2;
  g.inr3 = g.inr4 * x;
  float u = (x - 5.8f) * 5.0f;              // (x-RMIN)/(RMAX-RMIN)
  float uu = u * u;
  float A = -6.0f * uu + 15.0f * u - 10.0f;
  float poly = uu * u * A + 1.0f;
  float dpoly = (3.0f * uu * A + uu * u * (-12.0f * u + 15.0f)) * 5.0f;
  bool mid = (x >= 5.8f) && (x < 6.0f);
  g.vv = ((x < 5.8f) ? 1.0f : (mid ? poly : 0.0f)) * g.mf;
  g.dvv = (mid ? dpoly : 0.0f) * g.mf;
  return g;
}

// Normalized descriptor channels blk[4]; also returns 1/dstd per channel.
DEV void geom_blk(const Geom& g, float dx, float dy, float dz, int t, int m,
                  const float* __restrict__ davg, const float* __restrict__ dstd,
                  float* __restrict__ blk, float* __restrict__ rsv) {
  int bidx = (t * M_ + m) * 4;
  float4 av = *(const float4*)(davg + bidx);
  float4 sv = *(const float4*)(dstd + bidx);
  float pre[4] = {g.inr, dx * g.inr2, dy * g.inr2, dz * g.inr2};
  float avf[4] = {av.x, av.y, av.z, av.w};
  float svf[4] = {sv.x, sv.y, sv.z, sv.w};
#pragma unroll
  for (int d = 0; d < 4; ++d) {
    rsv[d] = __builtin_amdgcn_rcpf(svf[d]);
    blk[d] = (pre[d] * g.vv - avf[d]) * rsv[d];
  }
}

// K1: per atom (block), per neighbor (thread): geometry + lean embedding fwd,
// then acc[4][25] = CSC * sum_m blk[m][d] * G[m][e] via LDS reduction.
__global__ __launch_bounds__(256) void k_embed_acc(
    const float* __restrict__ dR, const int* __restrict__ neigh,
    const float* __restrict__ davg, const float* __restrict__ dstd,
    const float* __restrict__ eW0, const float* __restrict__ eb0,
    const float* __restrict__ eW1, const float* __restrict__ eb1,
    const float* __restrict__ eW2, const float* __restrict__ eb2,
    float* __restrict__ acc_ws) {
  __shared__ float sG[M_ * D_];
  __shared__ float4 sBlk[M_];
  int atom = blockIdx.x;
  int n = atom & (N_ - 1);
  int t = (n >= 512) ? 1 : 0;
  int m = threadIdx.x;
  // pair index is uniform across each 64-lane wave (m>>7 constant per wave)
  int p = __builtin_amdgcn_readfirstlane(t * 2 + (m >> 7));
  const float* W0 = eW0 + p * D_;
  const float* b0 = eb0 + p * D_;
  const float* W1 = eW1 + p * D_ * D_;
  const float* b1 = eb1 + p * D_;
  const float* W2 = eW2 + p * D_ * D_;
  const float* b2 = eb2 + p * D_;
  int base = atom * M_ + m;
  float dx = dR[base * 3 + 0];
  float dy = dR[base * 3 + 1];
  float dz = dR[base * 3 + 2];
  int nb = neigh[base];
  Geom g = geom_core(dx, dy, dz, nb);
  float blk[4], rsv[4];
  geom_blk(g, dx, dy, dz, t, m, davg, dstd, blk, rsv);
  float s = blk[0];
  float h[D_], a[D_];
#pragma unroll
  for (int e = 0; e < D_; ++e) h[e] = fast_tanh(fmaf(s, W0[e], b0[e]));
#pragma unroll
  for (int e = 0; e < D_; ++e) a[e] = b1[e];
#pragma unroll
  for (int f = 0; f < D_; ++f) {
    float hf = h[f];
#pragma unroll
    for (int e = 0; e < D_; ++e) a[e] = fmaf(hf, W1[f * D_ + e], a[e]);
  }
#pragma unroll
  for (int e = 0; e < D_; ++e) h[e] += fast_tanh(a[e]);   // h1
#pragma unroll
  for (int e = 0; e < D_; ++e) a[e] = b2[e];
#pragma unroll
  for (int f = 0; f < D_; ++f) {
    float hf = h[f];
#pragma unroll
    for (int e = 0; e < D_; ++e) a[e] = fmaf(hf, W2[f * D_ + e], a[e]);
  }
#pragma unroll
  for (int e = 0; e < D_; ++e) sG[m * D_ + e] = h[e] + fast_tanh(a[e]);  // G
  sBlk[m] = make_float4(blk[0], blk[1], blk[2], blk[3]);
  __syncthreads();
  if (threadIdx.x < 100) {
    int d = threadIdx.x & 3;
    int e = threadIdx.x >> 2;
    const float* sb = (const float*)sBlk;
    // 4-way partial sums: break the serial fma/ds_read dependence chain
    float s0 = 0.0f, s1 = 0.0f, s2 = 0.0f, s3 = 0.0f;
    for (int mm = 0; mm < M_; mm += 4) {
      s0 = fmaf(sb[(mm + 0) * 4 + d], sG[(mm + 0) * D_ + e], s0);
      s1 = fmaf(sb[(mm + 1) * 4 + d], sG[(mm + 1) * D_ + e], s1);
      s2 = fmaf(sb[(mm + 2) * 4 + d], sG[(mm + 2) * D_ + e], s2);
      s3 = fmaf(sb[(mm + 3) * 4 + d], sG[(mm + 3) * D_ + e], s3);
    }
    acc_ws[atom * 100 + d * D_ + e] = ((s0 + s1) + (s2 + s3)) * CSC;
  }
}

// K2: 8 atoms per block. DRt + fitting net fwd + bwd, emits Ei/Etot and dacc.
__global__ __launch_bounds__(256) void k_fit(
    const float* __restrict__ acc_ws,
    const float* __restrict__ fW0, const float* __restrict__ fb0,
    const float* __restrict__ fW1, const float* __restrict__ fb1,
    const float* __restrict__ fW2, const float* __restrict__ fb2,
    const float* __restrict__ fW3, const float* __restrict__ fb3,
    const float* __restrict__ ener_shift,
    float* __restrict__ dacc_ws, float* __restrict__ out) {
  constexpr int AB = 8;
  __shared__ float sAcc[AB][100];
  __shared__ float sX[AB][400];   // x fwd, then dx bwd
  __shared__ float sH0[AB][FH_];  // h0, then g0
  __shared__ float sT1[AB][FH_];  // tanh1, then g1
  __shared__ float sH1[AB][FH_];  // h1, then dh1
  __shared__ float sT2[AB][FH_];  // tanh2, then g2
  __shared__ float sEi[AB];
  int a0 = blockIdx.x * AB;
  int bb = a0 >> 10;
  int n0 = a0 & (N_ - 1);
  int t = (n0 >= 512) ? 1 : 0;
  int tid = threadIdx.x;
  for (int idx = tid; idx < AB * 100; idx += 256)
    ((float*)sAcc)[idx] = acc_ws[a0 * 100 + idx];
  if (tid < AB) sEi[tid] = 0.0f;
  __syncthreads();
  // DRt[e][f] = sum_d acc[d][e]*acc[d][f], f<16
  for (int idx = tid; idx < AB * 400; idx += 256) {
    int a = idx / 400; int r = idx % 400; int e = r >> 4; int f = r & 15;
    const float* A = sAcc[a];
    sX[a][r] = A[e] * A[f] + A[25 + e] * A[25 + f] + A[50 + e] * A[50 + f] +
               A[75 + e] * A[75 + f];
  }
  __syncthreads();
  const float* W0 = fW0 + t * 400 * FH_;
  const float* W1 = fW1 + t * FH_ * FH_;
  const float* W2 = fW2 + t * FH_ * FH_;
  const float* B0 = fb0 + t * FH_;
  const float* B1 = fb1 + t * FH_;
  const float* B2 = fb2 + t * FH_;
  const float* W3 = fW3 + t * FH_;
  int j = tid;
  if (j < FH_) {  // layer 0: 400 -> 240
    float acc8[AB];
#pragma unroll
    for (int a = 0; a < AB; ++a) acc8[a] = B0[j];
    for (int i = 0; i < 400; ++i) {
      float w = W0[i * FH_ + j];
#pragma unroll
      for (int a = 0; a < AB; ++a) acc8[a] = fmaf(sX[a][i], w, acc8[a]);
    }
#pragma unroll
    for (int a = 0; a < AB; ++a) sH0[a][j] = fast_tanh(acc8[a]);
  }
  __syncthreads();
  if (j < FH_) {  // layer 1 (residual)
    float acc8[AB];
#pragma unroll
    for (int a = 0; a < AB; ++a) acc8[a] = B1[j];
    for (int f = 0; f < FH_; ++f) {
      float w = W1[f * FH_ + j];
#pragma unroll
      for (int a = 0; a < AB; ++a) acc8[a] = fmaf(sH0[a][f], w, acc8[a]);
    }
#pragma unroll
    for (int a = 0; a < AB; ++a) {
      float tv = fast_tanh(acc8[a]);
      sT1[a][j] = tv;
      sH1[a][j] = sH0[a][j] + tv;
    }
  }
  __syncthreads();
  if (j < FH_) {  // layer 2 (residual) + Ei dot
    float acc8[AB];
#pragma unroll
    for (int a = 0; a < AB; ++a) acc8[a] = B2[j];
    for (int f = 0; f < FH_; ++f) {
      float w = W2[f * FH_ + j];
#pragma unroll
      for (int a = 0; a < AB; ++a) acc8[a] = fmaf(sH1[a][f], w, acc8[a]);
    }
    float w3 = W3[j];
#pragma unroll
    for (int a = 0; a < AB; ++a) {
      float tv = fast_tanh(acc8[a]);
      sT2[a][j] = tv;
      atomicAdd(&sEi[a], (sH1[a][j] + tv) * w3);
    }
  }
  __syncthreads();
  if (tid < AB) {
    float ei = sEi[tid] + fb3[t] + ener_shift[t];
    out[8 + a0 + tid] = ei;            // Ei
    atomicAdd(&out[bb], ei);           // Etot
  }
  if (j < FH_) {  // g2 = W3 * (1 - t2^2)   (dEi = 1)
    float w3 = W3[j];
#pragma unroll
    for (int a = 0; a < AB; ++a) {
      float tv = sT2[a][j];
      sT2[a][j] = w3 * (1.0f - tv * tv);
    }
  }
  __syncthreads();
  if (j < FH_) {  // dh1 = W3 + g2 @ W2^T ; g1 = dh1*(1-t1^2)
    float w3 = W3[j];
    float acc8[AB];
#pragma unroll
    for (int a = 0; a < AB; ++a) acc8[a] = w3;
    for (int k = 0; k < FH_; ++k) {
      float w = W2[j * FH_ + k];
#pragma unroll
      for (int a = 0; a < AB; ++a) acc8[a] = fmaf(sT2[a][k], w, acc8[a]);
    }
#pragma unroll
    for (int a = 0; a < AB; ++a) {
      float dh1 = acc8[a];
      float tv = sT1[a][j];
      sH1[a][j] = dh1;
      sT1[a][j] = dh1 * (1.0f - tv * tv);
    }
  }
  __syncthreads();
  if (j < FH_) {  // dh0 = dh1 + g1 @ W1^T ; g0 = dh0*(1-h0^2)
    float acc8[AB];
#pragma unroll
    for (int a = 0; a < AB; ++a) acc8[a] = sH1[a][j];
    for (int k = 0; k < FH_; ++k) {
      float w = W1[j * FH_ + k];
#pragma unroll
      for (int a = 0; a < AB; ++a) acc8[a] = fmaf(sT1[a][k], w, acc8[a]);
    }
#pragma unroll
    for (int a = 0; a < AB; ++a) {
      float h0v = sH0[a][j];
      sH0[a][j] = acc8[a] * (1.0f - h0v * h0v);
    }
  }
  __syncthreads();
  // dx = g0 @ W0^T  (overwrite sX)
  for (int i = tid; i < 400; i += 256) {
    float acc8[AB];
#pragma unroll
    for (int a = 0; a < AB; ++a) acc8[a] = 0.0f;
    for (int jj = 0; jj < FH_; ++jj) {
      float w = W0[i * FH_ + jj];
#pragma unroll
      for (int a = 0; a < AB; ++a) acc8[a] = fmaf(sH0[a][jj], w, acc8[a]);
    }
#pragma unroll
    for (int a = 0; a < AB; ++a) sX[a][i] = acc8[a];
  }
  __syncthreads();
  // dacc[d][e] = sum_{f<16} dDRt[e][f]*acc[d][f] + [e<16] sum_e2 dDRt[e2][e]*acc[d][e2]
  for (int idx = tid; idx < AB * 100; idx += 256) {
    int a = idx / 100; int r = idx % 100; int d = r / 25; int e = r % 25;
    const float* A = sAcc[a];
    const float* DX = sX[a];
    float sum = 0.0f;
#pragma unroll
    for (int f = 0; f < 16; ++f) sum = fmaf(DX[e * 16 + f], A[d * 25 + f], sum);
    if (e < 16) {
#pragma unroll
      for (int e2 = 0; e2 < 25; ++e2) sum = fmaf(DX[e2 * 16 + e], A[d * 25 + e2], sum);
    }
    dacc_ws[a0 * 100 + idx] = sum;
  }
}

// K3: R1's PROVEN clean kernel (pure-register JVP, ZERO LDS, 88 VGPR, no
// spill: FETCH was 20MB) — but with 5 waves/SIMD instead of R1's hard cap
// of 2. Theory: the ~550us invariant is the serialized s_load weight chain
// (~150 dependent batches x ~220cyc = ~34K stall cycles/wave/atom vs 7K VALU
// cycles); every prior round ran it at only 2 effective waves/SIMD (R1:
// waves_per_eu(2,2) max-cap; R5: grid 512 = 2 blocks/CU). Latency chains
// hide only via resident waves. waves_per_eu(5,5): VGPR budget 102 >= the
// proven 88-reg fit (NOT the R6 failure mode: that forced 64 on a GATOMS
// loop that couldn't remat). Zero LDS -> residency limited only by VGPRs.
// Global atomics restored (R3 vs R5 proved them equivalent to LDS bins).
__global__ __launch_bounds__(256) __attribute__((amdgpu_waves_per_eu(5, 5)))
void k_bwd_force(
    const float* __restrict__ dR, const int* __restrict__ neigh,
    const float* __restrict__ davg, const float* __restrict__ dstd,
    const float* __restrict__ eW0, const float* __restrict__ eb0,
    const float* __restrict__ eW1, const float* __restrict__ eb1,
    const float* __restrict__ eW2, const float* __restrict__ eb2,
    const float* __restrict__ dacc_ws, float* __restrict__ out) {
  int atom = blockIdx.x;
  int bb = atom >> 10;
  int n = atom & (N_ - 1);
  int t = (n >= 512) ? 1 : 0;
  int m = threadIdx.x;
  int p = __builtin_amdgcn_readfirstlane(t * 2 + (m >> 7));
  const float* W0 = eW0 + p * D_;
  const float* b0 = eb0 + p * D_;
  const float* W1 = eW1 + p * D_ * D_;
  const float* b1 = eb1 + p * D_;
  const float* W2 = eW2 + p * D_ * D_;
  const float* b2 = eb2 + p * D_;
  const float* dac = dacc_ws + atom * 100;  // block-uniform -> scalar loads
  int base = atom * M_ + m;
  float dx = dR[base * 3 + 0];
  float dy = dR[base * 3 + 1];
  float dz = dR[base * 3 + 2];
  int nb = neigh[base];
  Geom g = geom_core(dx, dy, dz, nb);
  float blk[4], rsv[4];
  geom_blk(g, dx, dy, dz, t, m, davg, dstd, blk, rsv);

  // ---- fused forward + d/ds (JVP) through the embedding MLP ----
  float s = blk[0];
  float h[D_], hp[D_];          // value, d/ds
#pragma unroll
  for (int e = 0; e < D_; ++e) {
    float th = fast_tanh(fmaf(s, W0[e], b0[e]));
    h[e] = th;
    hp[e] = (1.0f - th * th) * W0[e];
  }
  {  // layer 1 (residual)
    float a[D_], ap[D_];
#pragma unroll
    for (int e = 0; e < D_; ++e) { a[e] = b1[e]; ap[e] = 0.0f; }
#pragma unroll
    for (int f = 0; f < D_; ++f) {
      float hf = h[f], gf = hp[f];
#pragma unroll
      for (int e = 0; e < D_; ++e) {
        float w = W1[f * D_ + e];
        a[e] = fmaf(hf, w, a[e]);
        ap[e] = fmaf(gf, w, ap[e]);
      }
    }
#pragma unroll
    for (int e = 0; e < D_; ++e) {
      float th = fast_tanh(a[e]);
      h[e] += th;
      hp[e] = fmaf(1.0f - th * th, ap[e], hp[e]);
    }
  }
  {  // layer 2 (residual) -> h = G, hp = dG/ds
    float a[D_], ap[D_];
#pragma unroll
    for (int e = 0; e < D_; ++e) { a[e] = b2[e]; ap[e] = 0.0f; }
#pragma unroll
    for (int f = 0; f < D_; ++f) {
      float hf = h[f], gf = hp[f];
#pragma unroll
      for (int e = 0; e < D_; ++e) {
        float w = W2[f * D_ + e];
        a[e] = fmaf(hf, w, a[e]);
        ap[e] = fmaf(gf, w, ap[e]);
      }
    }
#pragma unroll
    for (int e = 0; e < D_; ++e) {
      float th = fast_tanh(a[e]);
      h[e] += th;
      hp[e] = fmaf(1.0f - th * th, ap[e], hp[e]);
    }
  }

  // ---- gradients: dE[d] = CSC*(sum_e dac[d][e]*G[e]) + [d==0] ds ----
  float ds = 0.0f, db0 = 0.0f, db1 = 0.0f, db2 = 0.0f, db3 = 0.0f;
#pragma unroll
  for (int e = 0; e < D_; ++e) {
    float d0 = dac[e], d1 = dac[25 + e], d2 = dac[50 + e], d3 = dac[75 + e];
    float gG = d0 * blk[0] + d1 * blk[1] + d2 * blk[2] + d3 * blk[3];
    ds = fmaf(gG, hp[e], ds);
    float he = h[e];
    db0 = fmaf(d0, he, db0);
    db1 = fmaf(d1, he, db1);
    db2 = fmaf(d2, he, db2);
    db3 = fmaf(d3, he, db3);
  }
  float dE0 = (db0 + ds) * CSC;
  float dE1 = db1 * CSC, dE2 = db2 * CSC, dE3 = db3 * CSC;

  // ---- fold the 4x3 geometry Jacobian directly into the force vector ----
  float dv[3] = {dx, dy, dz};
  float pre1[3] = {dx * g.inr2, dy * g.inr2, dz * g.inr2};
  float ci = g.dvv * g.inr;
  float com[3];
#pragma unroll
  for (int c = 0; c < 3; ++c) com[c] = ci * dv[c];
  float iv = g.inr3 * g.vv;
  float pc[3];
  float f0 = dE0 * rsv[0];
#pragma unroll
  for (int c = 0; c < 3; ++c) pc[c] = f0 * (dv[c] * iv - g.inr * com[c]);
  float dEr[3] = {dE1, dE2, dE3};
#pragma unroll
  for (int r = 0; r < 3; ++r) {
    float fr = dEr[r] * rsv[1 + r];
#pragma unroll
    for (int c = 0; c < 3; ++c) {
      float outer = 2.0f * dv[r] * dv[c] * g.inr4 - ((r == c) ? g.inr2 : 0.0f);
      pc[c] = fmaf(fr, outer * g.vv - pre1[r] * com[c], pc[c]);
    }
  }
  float px = pc[0] * g.mf, py = pc[1] * g.mf, pz = pc[2] * g.mf;

  if (nb > 0) {  // scatter to neighbor j = nb-1
    int jn = nb - 1;
    int fi = 8 + NATOM + (bb * N_ + jn) * 3;
    atomicAdd(&out[fi + 0], px);
    atomicAdd(&out[fi + 1], py);
    atomicAdd(&out[fi + 2], pz);
  }
  // F_self: 64-lane shuffle reduce, one atomic per wave per component
#pragma unroll
  for (int i = 1; i < 64; i <<= 1) {
    px += __shfl_xor(px, i);
    py += __shfl_xor(py, i);
    pz += __shfl_xor(pz, i);
  }
  if ((m & 63) == 0) {
    int fi = 8 + NATOM + atom * 3;
    atomicAdd(&out[fi + 0], -px);
    atomicAdd(&out[fi + 1], -py);
    atomicAdd(&out[fi + 2], -pz);
  }
}

}  // namespace

extern "C" void kernel_launch(void* const* d_in, const int* in_sizes, int n_in,
                              void* d_out, int out_size, void* d_ws, size_t ws_size,
                              hipStream_t stream) {
  (void)in_sizes; (void)n_in; (void)ws_size;
  const float* image_dR   = (const float*)d_in[0];
  const int*   list_neigh = (const int*)d_in[1];
  const float* davg       = (const float*)d_in[2];
  const float* dstd       = (const float*)d_in[3];
  const float* eW0        = (const float*)d_in[4];
  const float* eb0        = (const float*)d_in[5];
  const float* eW1        = (const float*)d_in[6];
  const float* eb1        = (const float*)d_in[7];
  const float* eW2        = (const float*)d_in[8];
  const float* eb2        = (const float*)d_in[9];
  const float* fW0        = (const float*)d_in[10];
  const float* fb0        = (const float*)d_in[11];
  const float* fW1        = (const float*)d_in[12];
  const float* fb1        = (const float*)d_in[13];
  const float* fW2        = (const float*)d_in[14];
  const float* fb2        = (const float*)d_in[15];
  const float* fW3        = (const float*)d_in[16];
  const float* fb3        = (const float*)d_in[17];
  const float* ener_shift = (const float*)d_in[18];
  float* out = (float*)d_out;
  float* acc_ws  = (float*)d_ws;                  // 8192*100 floats
  float* dacc_ws = acc_ws + NATOM * 100;          // 8192*100 floats

  hipMemsetAsync(d_out, 0, (size_t)out_size * sizeof(float), stream);
  k_embed_acc<<<NATOM, 256, 0, stream>>>(image_dR, list_neigh, davg, dstd,
                                         eW0, eb0, eW1, eb1, eW2, eb2, acc_ws);
  k_fit<<<NATOM / 8, 256, 0, stream>>>(acc_ws, fW0, fb0, fW1, fb1, fW2, fb2,
                                       fW3, fb3, ener_shift, dacc_ws, out);
  k_bwd_force<<<NATOM, 256, 0, stream>>>(image_dR, list_neigh, davg, dstd,
                                         eW0, eb0, eW1, eb1, eW2, eb2,
                                         dacc_ws, out);
}

// Round 8
// 987.108 us; speedup vs baseline: 3.2542x; 1.8991x over previous
//
#include <hip/hip_runtime.h>

#define DEV __device__ __forceinline__

namespace {

constexpr int B_ = 8;
constexpr int N_ = 1024;
constexpr int M_ = 256;
constexpr int D_ = 25;
constexpr int FH_ = 240;
constexpr int NATOM = B_ * N_;          // 8192
constexpr float CSC = 1.0f / 256.0f;    // 4/(NN*NTYPES*4)

DEV float fast_tanh(float x) {
  float ax = fabsf(x);
  float e = __expf(-2.0f * ax);
  float r = (1.0f - e) * __builtin_amdgcn_rcpf(1.0f + e);
  return copysignf(r, x);
}

// Scalar geometry pieces shared by descriptor and Jacobian.
struct Geom {
  float mf, inr, inr2, inr4, inr3, vv, dvv;
};

DEV Geom geom_core(float dx, float dy, float dz, int nb) {
  Geom g;
  g.mf = (nb > 0) ? 1.0f : 0.0f;
  float dr2 = dx * dx + dy * dy + dz * dz;
  float safe = (nb > 0) ? dr2 : 1.0f;
  float rs = __builtin_amdgcn_rsqf(safe);   // 1/sqrt(safe)
  float rij = safe * rs;                    // sqrt(safe)
  g.inr = g.mf * rs;
  float x = rij * g.mf;
  g.inr2 = g.inr * g.inr;
  g.inr4 = g.inr2 * g.inr2;
  g.inr3 = g.inr4 * x;
  float u = (x - 5.8f) * 5.0f;              // (x-RMIN)/(RMAX-RMIN)
  float uu = u * u;
  float A = -6.0f * uu + 15.0f * u - 10.0f;
  float poly = uu * u * A + 1.0f;
  float dpoly = (3.0f * uu * A + uu * u * (-12.0f * u + 15.0f)) * 5.0f;
  bool mid = (x >= 5.8f) && (x < 6.0f);
  g.vv = ((x < 5.8f) ? 1.0f : (mid ? poly : 0.0f)) * g.mf;
  g.dvv = (mid ? dpoly : 0.0f) * g.mf;
  return g;
}

// Normalized descriptor channels blk[4]; also returns 1/dstd per channel.
DEV void geom_blk(const Geom& g, float dx, float dy, float dz, int t, int m,
                  const float* __restrict__ davg, const float* __restrict__ dstd,
                  float* __restrict__ blk, float* __restrict__ rsv) {
  int bidx = (t * M_ + m) * 4;
  float4 av = *(const float4*)(davg + bidx);
  float4 sv = *(const float4*)(dstd + bidx);
  float pre[4] = {g.inr, dx * g.inr2, dy * g.inr2, dz * g.inr2};
  float avf[4] = {av.x, av.y, av.z, av.w};
  float svf[4] = {sv.x, sv.y, sv.z, sv.w};
#pragma unroll
  for (int d = 0; d < 4; ++d) {
    rsv[d] = __builtin_amdgcn_rcpf(svf[d]);
    blk[d] = (pre[d] * g.vv - avf[d]) * rsv[d];
  }
}

// K1: per atom (block), per neighbor (thread): geometry + lean embedding fwd,
// then acc[4][25] = CSC * sum_m blk[m][d] * G[m][e] via LDS reduction.
__global__ __launch_bounds__(256) void k_embed_acc(
    const float* __restrict__ dR, const int* __restrict__ neigh,
    const float* __restrict__ davg, const float* __restrict__ dstd,
    const float* __restrict__ eW0, const float* __restrict__ eb0,
    const float* __restrict__ eW1, const float* __restrict__ eb1,
    const float* __restrict__ eW2, const float* __restrict__ eb2,
    float* __restrict__ acc_ws) {
  __shared__ float sG[M_ * D_];
  __shared__ float4 sBlk[M_];
  int atom = blockIdx.x;
  int n = atom & (N_ - 1);
  int t = (n >= 512) ? 1 : 0;
  int m = threadIdx.x;
  // pair index is uniform across each 64-lane wave (m>>7 constant per wave)
  int p = __builtin_amdgcn_readfirstlane(t * 2 + (m >> 7));
  const float* W0 = eW0 + p * D_;
  const float* b0 = eb0 + p * D_;
  const float* W1 = eW1 + p * D_ * D_;
  const float* b1 = eb1 + p * D_;
  const float* W2 = eW2 + p * D_ * D_;
  const float* b2 = eb2 + p * D_;
  int base = atom * M_ + m;
  float dx = dR[base * 3 + 0];
  float dy = dR[base * 3 + 1];
  float dz = dR[base * 3 + 2];
  int nb = neigh[base];
  Geom g = geom_core(dx, dy, dz, nb);
  float blk[4], rsv[4];
  geom_blk(g, dx, dy, dz, t, m, davg, dstd, blk, rsv);
  float s = blk[0];
  float h[D_], a[D_];
#pragma unroll
  for (int e = 0; e < D_; ++e) h[e] = fast_tanh(fmaf(s, W0[e], b0[e]));
#pragma unroll
  for (int e = 0; e < D_; ++e) a[e] = b1[e];
#pragma unroll
  for (int f = 0; f < D_; ++f) {
    float hf = h[f];
#pragma unroll
    for (int e = 0; e < D_; ++e) a[e] = fmaf(hf, W1[f * D_ + e], a[e]);
  }
#pragma unroll
  for (int e = 0; e < D_; ++e) h[e] += fast_tanh(a[e]);   // h1
#pragma unroll
  for (int e = 0; e < D_; ++e) a[e] = b2[e];
#pragma unroll
  for (int f = 0; f < D_; ++f) {
    float hf = h[f];
#pragma unroll
    for (int e = 0; e < D_; ++e) a[e] = fmaf(hf, W2[f * D_ + e], a[e]);
  }
#pragma unroll
  for (int e = 0; e < D_; ++e) sG[m * D_ + e] = h[e] + fast_tanh(a[e]);  // G
  sBlk[m] = make_float4(blk[0], blk[1], blk[2], blk[3]);
  __syncthreads();
  if (threadIdx.x < 100) {
    int d = threadIdx.x & 3;
    int e = threadIdx.x >> 2;
    const float* sb = (const float*)sBlk;
    // 4-way partial sums: break the serial fma/ds_read dependence chain
    float s0 = 0.0f, s1 = 0.0f, s2 = 0.0f, s3 = 0.0f;
    for (int mm = 0; mm < M_; mm += 4) {
      s0 = fmaf(sb[(mm + 0) * 4 + d], sG[(mm + 0) * D_ + e], s0);
      s1 = fmaf(sb[(mm + 1) * 4 + d], sG[(mm + 1) * D_ + e], s1);
      s2 = fmaf(sb[(mm + 2) * 4 + d], sG[(mm + 2) * D_ + e], s2);
      s3 = fmaf(sb[(mm + 3) * 4 + d], sG[(mm + 3) * D_ + e], s3);
    }
    acc_ws[atom * 100 + d * D_ + e] = ((s0 + s1) + (s2 + s3)) * CSC;
  }
}

// K2: 8 atoms per block. DRt + fitting net fwd + bwd, emits Ei/Etot and dacc.
__global__ __launch_bounds__(256) void k_fit(
    const float* __restrict__ acc_ws,
    const float* __restrict__ fW0, const float* __restrict__ fb0,
    const float* __restrict__ fW1, const float* __restrict__ fb1,
    const float* __restrict__ fW2, const float* __restrict__ fb2,
    const float* __restrict__ fW3, const float* __restrict__ fb3,
    const float* __restrict__ ener_shift,
    float* __restrict__ dacc_ws, float* __restrict__ out) {
  constexpr int AB = 8;
  __shared__ float sAcc[AB][100];
  __shared__ float sX[AB][400];   // x fwd, then dx bwd
  __shared__ float sH0[AB][FH_];  // h0, then g0
  __shared__ float sT1[AB][FH_];  // tanh1, then g1
  __shared__ float sH1[AB][FH_];  // h1, then dh1
  __shared__ float sT2[AB][FH_];  // tanh2, then g2
  __shared__ float sEi[AB];
  int a0 = blockIdx.x * AB;
  int bb = a0 >> 10;
  int n0 = a0 & (N_ - 1);
  int t = (n0 >= 512) ? 1 : 0;
  int tid = threadIdx.x;
  for (int idx = tid; idx < AB * 100; idx += 256)
    ((float*)sAcc)[idx] = acc_ws[a0 * 100 + idx];
  if (tid < AB) sEi[tid] = 0.0f;
  __syncthreads();
  // DRt[e][f] = sum_d acc[d][e]*acc[d][f], f<16
  for (int idx = tid; idx < AB * 400; idx += 256) {
    int a = idx / 400; int r = idx % 400; int e = r >> 4; int f = r & 15;
    const float* A = sAcc[a];
    sX[a][r] = A[e] * A[f] + A[25 + e] * A[25 + f] + A[50 + e] * A[50 + f] +
               A[75 + e] * A[75 + f];
  }
  __syncthreads();
  const float* W0 = fW0 + t * 400 * FH_;
  const float* W1 = fW1 + t * FH_ * FH_;
  const float* W2 = fW2 + t * FH_ * FH_;
  const float* B0 = fb0 + t * FH_;
  const float* B1 = fb1 + t * FH_;
  const float* B2 = fb2 + t * FH_;
  const float* W3 = fW3 + t * FH_;
  int j = tid;
  if (j < FH_) {  // layer 0: 400 -> 240
    float acc8[AB];
#pragma unroll
    for (int a = 0; a < AB; ++a) acc8[a] = B0[j];
    for (int i = 0; i < 400; ++i) {
      float w = W0[i * FH_ + j];
#pragma unroll
      for (int a = 0; a < AB; ++a) acc8[a] = fmaf(sX[a][i], w, acc8[a]);
    }
#pragma unroll
    for (int a = 0; a < AB; ++a) sH0[a][j] = fast_tanh(acc8[a]);
  }
  __syncthreads();
  if (j < FH_) {  // layer 1 (residual)
    float acc8[AB];
#pragma unroll
    for (int a = 0; a < AB; ++a) acc8[a] = B1[j];
    for (int f = 0; f < FH_; ++f) {
      float w = W1[f * FH_ + j];
#pragma unroll
      for (int a = 0; a < AB; ++a) acc8[a] = fmaf(sH0[a][f], w, acc8[a]);
    }
#pragma unroll
    for (int a = 0; a < AB; ++a) {
      float tv = fast_tanh(acc8[a]);
      sT1[a][j] = tv;
      sH1[a][j] = sH0[a][j] + tv;
    }
  }
  __syncthreads();
  if (j < FH_) {  // layer 2 (residual) + Ei dot
    float acc8[AB];
#pragma unroll
    for (int a = 0; a < AB; ++a) acc8[a] = B2[j];
    for (int f = 0; f < FH_; ++f) {
      float w = W2[f * FH_ + j];
#pragma unroll
      for (int a = 0; a < AB; ++a) acc8[a] = fmaf(sH1[a][f], w, acc8[a]);
    }
    float w3 = W3[j];
#pragma unroll
    for (int a = 0; a < AB; ++a) {
      float tv = fast_tanh(acc8[a]);
      sT2[a][j] = tv;
      atomicAdd(&sEi[a], (sH1[a][j] + tv) * w3);
    }
  }
  __syncthreads();
  if (tid < AB) {
    float ei = sEi[tid] + fb3[t] + ener_shift[t];
    out[8 + a0 + tid] = ei;            // Ei
    atomicAdd(&out[bb], ei);           // Etot
  }
  if (j < FH_) {  // g2 = W3 * (1 - t2^2)   (dEi = 1)
    float w3 = W3[j];
#pragma unroll
    for (int a = 0; a < AB; ++a) {
      float tv = sT2[a][j];
      sT2[a][j] = w3 * (1.0f - tv * tv);
    }
  }
  __syncthreads();
  if (j < FH_) {  // dh1 = W3 + g2 @ W2^T ; g1 = dh1*(1-t1^2)
    float w3 = W3[j];
    float acc8[AB];
#pragma unroll
    for (int a = 0; a < AB; ++a) acc8[a] = w3;
    for (int k = 0; k < FH_; ++k) {
      float w = W2[j * FH_ + k];
#pragma unroll
      for (int a = 0; a < AB; ++a) acc8[a] = fmaf(sT2[a][k], w, acc8[a]);
    }
#pragma unroll
    for (int a = 0; a < AB; ++a) {
      float dh1 = acc8[a];
      float tv = sT1[a][j];
      sH1[a][j] = dh1;
      sT1[a][j] = dh1 * (1.0f - tv * tv);
    }
  }
  __syncthreads();
  if (j < FH_) {  // dh0 = dh1 + g1 @ W1^T ; g0 = dh0*(1-h0^2)
    float acc8[AB];
#pragma unroll
    for (int a = 0; a < AB; ++a) acc8[a] = sH1[a][j];
    for (int k = 0; k < FH_; ++k) {
      float w = W1[j * FH_ + k];
#pragma unroll
      for (int a = 0; a < AB; ++a) acc8[a] = fmaf(sT1[a][k], w, acc8[a]);
    }
#pragma unroll
    for (int a = 0; a < AB; ++a) {
      float h0v = sH0[a][j];
      sH0[a][j] = acc8[a] * (1.0f - h0v * h0v);
    }
  }
  __syncthreads();
  // dx = g0 @ W0^T  (overwrite sX)
  for (int i = tid; i < 400; i += 256) {
    float acc8[AB];
#pragma unroll
    for (int a = 0; a < AB; ++a) acc8[a] = 0.0f;
    for (int jj = 0; jj < FH_; ++jj) {
      float w = W0[i * FH_ + jj];
#pragma unroll
      for (int a = 0; a < AB; ++a) acc8[a] = fmaf(sH0[a][jj], w, acc8[a]);
    }
#pragma unroll
    for (int a = 0; a < AB; ++a) sX[a][i] = acc8[a];
  }
  __syncthreads();
  // dacc[d][e] = sum_{f<16} dDRt[e][f]*acc[d][f] + [e<16] sum_e2 dDRt[e2][e]*acc[d][e2]
  for (int idx = tid; idx < AB * 100; idx += 256) {
    int a = idx / 100; int r = idx % 100; int d = r / 25; int e = r % 25;
    const float* A = sAcc[a];
    const float* DX = sX[a];
    float sum = 0.0f;
#pragma unroll
    for (int f = 0; f < 16; ++f) sum = fmaf(DX[e * 16 + f], A[d * 25 + f], sum);
    if (e < 16) {
#pragma unroll
      for (int e2 = 0; e2 < 25; ++e2) sum = fmaf(DX[e2 * 16 + e], A[d * 25 + e2], sum);
    }
    dacc_ws[a0 * 100 + idx] = sum;
  }
}

// K3: pure-register JVP (proven no-spill at 88 VGPR under (2,2), R1).
// R7 ((5,5)) proved the limiter was wave starvation: at 56% occupancy
// VALUBusy hit 96% — but the allocator overshot to 48 VGPR and spilled
// (FETCH 20->40MB, WRITE +155MB), inflating the instruction stream 2.5x.
// Cycle budget: ~7.6K VALU cyc/wave x 32 waves/SIMD => ~101us K3 floor at
// full duty. This round: (4,4) — budget 512/4 = 128 >= proven 88-reg fit
// (40 regs headroom), min=max so the scheduler has no incentive to shrink
// for extra occupancy (the (2,2) precedent: allocated exactly its need).
// Falsifier: VGPR<=64 + FETCH>>20MB again => attribute ladder unusable at
// min>=4; next round engineers live set <=64 structurally.
__global__ __launch_bounds__(256) __attribute__((amdgpu_waves_per_eu(4, 4)))
void k_bwd_force(
    const float* __restrict__ dR, const int* __restrict__ neigh,
    const float* __restrict__ davg, const float* __restrict__ dstd,
    const float* __restrict__ eW0, const float* __restrict__ eb0,
    const float* __restrict__ eW1, const float* __restrict__ eb1,
    const float* __restrict__ eW2, const float* __restrict__ eb2,
    const float* __restrict__ dacc_ws, float* __restrict__ out) {
  int atom = blockIdx.x;
  int bb = atom >> 10;
  int n = atom & (N_ - 1);
  int t = (n >= 512) ? 1 : 0;
  int m = threadIdx.x;
  int p = __builtin_amdgcn_readfirstlane(t * 2 + (m >> 7));
  const float* W0 = eW0 + p * D_;
  const float* b0 = eb0 + p * D_;
  const float* W1 = eW1 + p * D_ * D_;
  const float* b1 = eb1 + p * D_;
  const float* W2 = eW2 + p * D_ * D_;
  const float* b2 = eb2 + p * D_;
  const float* dac = dacc_ws + atom * 100;  // block-uniform -> scalar loads
  int base = atom * M_ + m;
  float dx = dR[base * 3 + 0];
  float dy = dR[base * 3 + 1];
  float dz = dR[base * 3 + 2];
  int nb = neigh[base];
  Geom g = geom_core(dx, dy, dz, nb);
  float blk[4], rsv[4];
  geom_blk(g, dx, dy, dz, t, m, davg, dstd, blk, rsv);

  // ---- fused forward + d/ds (JVP) through the embedding MLP ----
  float s = blk[0];
  float h[D_], hp[D_];          // value, d/ds
#pragma unroll
  for (int e = 0; e < D_; ++e) {
    float th = fast_tanh(fmaf(s, W0[e], b0[e]));
    h[e] = th;
    hp[e] = (1.0f - th * th) * W0[e];
  }
  {  // layer 1 (residual)
    float a[D_], ap[D_];
#pragma unroll
    for (int e = 0; e < D_; ++e) { a[e] = b1[e]; ap[e] = 0.0f; }
#pragma unroll
    for (int f = 0; f < D_; ++f) {
      float hf = h[f], gf = hp[f];
#pragma unroll
      for (int e = 0; e < D_; ++e) {
        float w = W1[f * D_ + e];
        a[e] = fmaf(hf, w, a[e]);
        ap[e] = fmaf(gf, w, ap[e]);
      }
    }
#pragma unroll
    for (int e = 0; e < D_; ++e) {
      float th = fast_tanh(a[e]);
      h[e] += th;
      hp[e] = fmaf(1.0f - th * th, ap[e], hp[e]);
    }
  }
  {  // layer 2 (residual) -> h = G, hp = dG/ds
    float a[D_], ap[D_];
#pragma unroll
    for (int e = 0; e < D_; ++e) { a[e] = b2[e]; ap[e] = 0.0f; }
#pragma unroll
    for (int f = 0; f < D_; ++f) {
      float hf = h[f], gf = hp[f];
#pragma unroll
      for (int e = 0; e < D_; ++e) {
        float w = W2[f * D_ + e];
        a[e] = fmaf(hf, w, a[e]);
        ap[e] = fmaf(gf, w, ap[e]);
      }
    }
#pragma unroll
    for (int e = 0; e < D_; ++e) {
      float th = fast_tanh(a[e]);
      h[e] += th;
      hp[e] = fmaf(1.0f - th * th, ap[e], hp[e]);
    }
  }

  // ---- gradients: dE[d] = CSC*(sum_e dac[d][e]*G[e]) + [d==0] ds ----
  float ds = 0.0f, db0 = 0.0f, db1 = 0.0f, db2 = 0.0f, db3 = 0.0f;
#pragma unroll
  for (int e = 0; e < D_; ++e) {
    float d0 = dac[e], d1 = dac[25 + e], d2 = dac[50 + e], d3 = dac[75 + e];
    float gG = d0 * blk[0] + d1 * blk[1] + d2 * blk[2] + d3 * blk[3];
    ds = fmaf(gG, hp[e], ds);
    float he = h[e];
    db0 = fmaf(d0, he, db0);
    db1 = fmaf(d1, he, db1);
    db2 = fmaf(d2, he, db2);
    db3 = fmaf(d3, he, db3);
  }
  float dE0 = (db0 + ds) * CSC;
  float dE1 = db1 * CSC, dE2 = db2 * CSC, dE3 = db3 * CSC;

  // ---- fold the 4x3 geometry Jacobian directly into the force vector ----
  float dv[3] = {dx, dy, dz};
  float pre1[3] = {dx * g.inr2, dy * g.inr2, dz * g.inr2};
  float ci = g.dvv * g.inr;
  float com[3];
#pragma unroll
  for (int c = 0; c < 3; ++c) com[c] = ci * dv[c];
  float iv = g.inr3 * g.vv;
  float pc[3];
  float f0 = dE0 * rsv[0];
#pragma unroll
  for (int c = 0; c < 3; ++c) pc[c] = f0 * (dv[c] * iv - g.inr * com[c]);
  float dEr[3] = {dE1, dE2, dE3};
#pragma unroll
  for (int r = 0; r < 3; ++r) {
    float fr = dEr[r] * rsv[1 + r];
#pragma unroll
    for (int c = 0; c < 3; ++c) {
      float outer = 2.0f * dv[r] * dv[c] * g.inr4 - ((r == c) ? g.inr2 : 0.0f);
      pc[c] = fmaf(fr, outer * g.vv - pre1[r] * com[c], pc[c]);
    }
  }
  float px = pc[0] * g.mf, py = pc[1] * g.mf, pz = pc[2] * g.mf;

  if (nb > 0) {  // scatter to neighbor j = nb-1
    int jn = nb - 1;
    int fi = 8 + NATOM + (bb * N_ + jn) * 3;
    atomicAdd(&out[fi + 0], px);
    atomicAdd(&out[fi + 1], py);
    atomicAdd(&out[fi + 2], pz);
  }
  // F_self: 64-lane shuffle reduce, one atomic per wave per component
#pragma unroll
  for (int i = 1; i < 64; i <<= 1) {
    px += __shfl_xor(px, i);
    py += __shfl_xor(py, i);
    pz += __shfl_xor(pz, i);
  }
  if ((m & 63) == 0) {
    int fi = 8 + NATOM + atom * 3;
    atomicAdd(&out[fi + 0], -px);
    atomicAdd(&out[fi + 1], -py);
    atomicAdd(&out[fi + 2], -pz);
  }
}

}  // namespace

extern "C" void kernel_launch(void* const* d_in, const int* in_sizes, int n_in,
                              void* d_out, int out_size, void* d_ws, size_t ws_size,
                              hipStream_t stream) {
  (void)in_sizes; (void)n_in; (void)ws_size;
  const float* image_dR   = (const float*)d_in[0];
  const int*   list_neigh = (const int*)d_in[1];
  const float* davg       = (const float*)d_in[2];
  const float* dstd       = (const float*)d_in[3];
  const float* eW0        = (const float*)d_in[4];
  const float* eb0        = (const float*)d_in[5];
  const float* eW1        = (const float*)d_in[6];
  const float* eb1        = (const float*)d_in[7];
  const float* eW2        = (const float*)d_in[8];
  const float* eb2        = (const float*)d_in[9];
  const float* fW0        = (const float*)d_in[10];
  const float* fb0        = (const float*)d_in[11];
  const float* fW1        = (const float*)d_in[12];
  const float* fb1        = (const float*)d_in[13];
  const float* fW2        = (const float*)d_in[14];
  const float* fb2        = (const float*)d_in[15];
  const float* fW3        = (const float*)d_in[16];
  const float* fb3        = (const float*)d_in[17];
  const float* ener_shift = (const float*)d_in[18];
  float* out = (float*)d_out;
  float* acc_ws  = (float*)d_ws;                  // 8192*100 floats
  float* dacc_ws = acc_ws + NATOM * 100;          // 8192*100 floats

  hipMemsetAsync(d_out, 0, (size_t)out_size * sizeof(float), stream);
  k_embed_acc<<<NATOM, 256, 0, stream>>>(image_dR, list_neigh, davg, dstd,
                                         eW0, eb0, eW1, eb1, eW2, eb2, acc_ws);
  k_fit<<<NATOM / 8, 256, 0, stream>>>(acc_ws, fW0, fb0, fW1, fb1, fW2, fb2,
                                       fW3, fb3, ener_shift, dacc_ws, out);
  k_bwd_force<<<NATOM, 256, 0, stream>>>(image_dR, list_neigh, davg, dstd,
                                         eW0, eb0, eW1, eb1, eW2, eb2,
                                         dacc_ws, out);
}

// Round 9
// 948.377 us; speedup vs baseline: 3.3871x; 1.0408x over previous
//
#include <hip/hip_runtime.h>

#define DEV __device__ __forceinline__

namespace {

constexpr int B_ = 8;
constexpr int N_ = 1024;
constexpr int M_ = 256;
constexpr int D_ = 25;
constexpr int FH_ = 240;
constexpr int NATOM = B_ * N_;          // 8192
constexpr float CSC = 1.0f / 256.0f;    // 4/(NN*NTYPES*4)

DEV float fast_tanh(float x) {
  float ax = fabsf(x);
  float e = __expf(-2.0f * ax);
  float r = (1.0f - e) * __builtin_amdgcn_rcpf(1.0f + e);
  return copysignf(r, x);
}

// Scalar geometry pieces shared by descriptor and Jacobian.
struct Geom {
  float mf, inr, inr2, inr4, inr3, vv, dvv;
};

DEV Geom geom_core(float dx, float dy, float dz, int nb) {
  Geom g;
  g.mf = (nb > 0) ? 1.0f : 0.0f;
  float dr2 = dx * dx + dy * dy + dz * dz;
  float safe = (nb > 0) ? dr2 : 1.0f;
  float rs = __builtin_amdgcn_rsqf(safe);   // 1/sqrt(safe)
  float rij = safe * rs;                    // sqrt(safe)
  g.inr = g.mf * rs;
  float x = rij * g.mf;
  g.inr2 = g.inr * g.inr;
  g.inr4 = g.inr2 * g.inr2;
  g.inr3 = g.inr4 * x;
  float u = (x - 5.8f) * 5.0f;              // (x-RMIN)/(RMAX-RMIN)
  float uu = u * u;
  float A = -6.0f * uu + 15.0f * u - 10.0f;
  float poly = uu * u * A + 1.0f;
  float dpoly = (3.0f * uu * A + uu * u * (-12.0f * u + 15.0f)) * 5.0f;
  bool mid = (x >= 5.8f) && (x < 6.0f);
  g.vv = ((x < 5.8f) ? 1.0f : (mid ? poly : 0.0f)) * g.mf;
  g.dvv = (mid ? dpoly : 0.0f) * g.mf;
  return g;
}

// Normalized descriptor channels blk[4]; also returns 1/dstd per channel.
DEV void geom_blk(const Geom& g, float dx, float dy, float dz, int t, int m,
                  const float* __restrict__ davg, const float* __restrict__ dstd,
                  float* __restrict__ blk, float* __restrict__ rsv) {
  int bidx = (t * M_ + m) * 4;
  float4 av = *(const float4*)(davg + bidx);
  float4 sv = *(const float4*)(dstd + bidx);
  float pre[4] = {g.inr, dx * g.inr2, dy * g.inr2, dz * g.inr2};
  float avf[4] = {av.x, av.y, av.z, av.w};
  float svf[4] = {sv.x, sv.y, sv.z, sv.w};
#pragma unroll
  for (int d = 0; d < 4; ++d) {
    rsv[d] = __builtin_amdgcn_rcpf(svf[d]);
    blk[d] = (pre[d] * g.vv - avf[d]) * rsv[d];
  }
}

// K1: per atom (block), per neighbor (thread): geometry + lean embedding fwd,
// then acc[4][25] = CSC * sum_m blk[m][d] * G[m][e] via LDS reduction.
__global__ __launch_bounds__(256) void k_embed_acc(
    const float* __restrict__ dR, const int* __restrict__ neigh,
    const float* __restrict__ davg, const float* __restrict__ dstd,
    const float* __restrict__ eW0, const float* __restrict__ eb0,
    const float* __restrict__ eW1, const float* __restrict__ eb1,
    const float* __restrict__ eW2, const float* __restrict__ eb2,
    float* __restrict__ acc_ws) {
  __shared__ float sG[M_ * D_];
  __shared__ float4 sBlk[M_];
  int atom = blockIdx.x;
  int n = atom & (N_ - 1);
  int t = (n >= 512) ? 1 : 0;
  int m = threadIdx.x;
  // pair index is uniform across each 64-lane wave (m>>7 constant per wave)
  int p = __builtin_amdgcn_readfirstlane(t * 2 + (m >> 7));
  const float* W0 = eW0 + p * D_;
  const float* b0 = eb0 + p * D_;
  const float* W1 = eW1 + p * D_ * D_;
  const float* b1 = eb1 + p * D_;
  const float* W2 = eW2 + p * D_ * D_;
  const float* b2 = eb2 + p * D_;
  int base = atom * M_ + m;
  float dx = dR[base * 3 + 0];
  float dy = dR[base * 3 + 1];
  float dz = dR[base * 3 + 2];
  int nb = neigh[base];
  Geom g = geom_core(dx, dy, dz, nb);
  float blk[4], rsv[4];
  geom_blk(g, dx, dy, dz, t, m, davg, dstd, blk, rsv);
  float s = blk[0];
  float h[D_], a[D_];
#pragma unroll
  for (int e = 0; e < D_; ++e) h[e] = fast_tanh(fmaf(s, W0[e], b0[e]));
#pragma unroll
  for (int e = 0; e < D_; ++e) a[e] = b1[e];
#pragma unroll
  for (int f = 0; f < D_; ++f) {
    float hf = h[f];
#pragma unroll
    for (int e = 0; e < D_; ++e) a[e] = fmaf(hf, W1[f * D_ + e], a[e]);
  }
#pragma unroll
  for (int e = 0; e < D_; ++e) h[e] += fast_tanh(a[e]);   // h1
#pragma unroll
  for (int e = 0; e < D_; ++e) a[e] = b2[e];
#pragma unroll
  for (int f = 0; f < D_; ++f) {
    float hf = h[f];
#pragma unroll
    for (int e = 0; e < D_; ++e) a[e] = fmaf(hf, W2[f * D_ + e], a[e]);
  }
#pragma unroll
  for (int e = 0; e < D_; ++e) sG[m * D_ + e] = h[e] + fast_tanh(a[e]);  // G
  sBlk[m] = make_float4(blk[0], blk[1], blk[2], blk[3]);
  __syncthreads();
  if (threadIdx.x < 100) {
    int d = threadIdx.x & 3;
    int e = threadIdx.x >> 2;
    const float* sb = (const float*)sBlk;
    // 4-way partial sums: break the serial fma/ds_read dependence chain
    float s0 = 0.0f, s1 = 0.0f, s2 = 0.0f, s3 = 0.0f;
    for (int mm = 0; mm < M_; mm += 4) {
      s0 = fmaf(sb[(mm + 0) * 4 + d], sG[(mm + 0) * D_ + e], s0);
      s1 = fmaf(sb[(mm + 1) * 4 + d], sG[(mm + 1) * D_ + e], s1);
      s2 = fmaf(sb[(mm + 2) * 4 + d], sG[(mm + 2) * D_ + e], s2);
      s3 = fmaf(sb[(mm + 3) * 4 + d], sG[(mm + 3) * D_ + e], s3);
    }
    acc_ws[atom * 100 + d * D_ + e] = ((s0 + s1) + (s2 + s3)) * CSC;
  }
}

// K2: 8 atoms per block. DRt + fitting net fwd + bwd, emits Ei/Etot and dacc.
__global__ __launch_bounds__(256) void k_fit(
    const float* __restrict__ acc_ws,
    const float* __restrict__ fW0, const float* __restrict__ fb0,
    const float* __restrict__ fW1, const float* __restrict__ fb1,
    const float* __restrict__ fW2, const float* __restrict__ fb2,
    const float* __restrict__ fW3, const float* __restrict__ fb3,
    const float* __restrict__ ener_shift,
    float* __restrict__ dacc_ws, float* __restrict__ out) {
  constexpr int AB = 8;
  __shared__ float sAcc[AB][100];
  __shared__ float sX[AB][400];   // x fwd, then dx bwd
  __shared__ float sH0[AB][FH_];  // h0, then g0
  __shared__ float sT1[AB][FH_];  // tanh1, then g1
  __shared__ float sH1[AB][FH_];  // h1, then dh1
  __shared__ float sT2[AB][FH_];  // tanh2, then g2
  __shared__ float sEi[AB];
  int a0 = blockIdx.x * AB;
  int bb = a0 >> 10;
  int n0 = a0 & (N_ - 1);
  int t = (n0 >= 512) ? 1 : 0;
  int tid = threadIdx.x;
  for (int idx = tid; idx < AB * 100; idx += 256)
    ((float*)sAcc)[idx] = acc_ws[a0 * 100 + idx];
  if (tid < AB) sEi[tid] = 0.0f;
  __syncthreads();
  // DRt[e][f] = sum_d acc[d][e]*acc[d][f], f<16
  for (int idx = tid; idx < AB * 400; idx += 256) {
    int a = idx / 400; int r = idx % 400; int e = r >> 4; int f = r & 15;
    const float* A = sAcc[a];
    sX[a][r] = A[e] * A[f] + A[25 + e] * A[25 + f] + A[50 + e] * A[50 + f] +
               A[75 + e] * A[75 + f];
  }
  __syncthreads();
  const float* W0 = fW0 + t * 400 * FH_;
  const float* W1 = fW1 + t * FH_ * FH_;
  const float* W2 = fW2 + t * FH_ * FH_;
  const float* B0 = fb0 + t * FH_;
  const float* B1 = fb1 + t * FH_;
  const float* B2 = fb2 + t * FH_;
  const float* W3 = fW3 + t * FH_;
  int j = tid;
  if (j < FH_) {  // layer 0: 400 -> 240
    float acc8[AB];
#pragma unroll
    for (int a = 0; a < AB; ++a) acc8[a] = B0[j];
    for (int i = 0; i < 400; ++i) {
      float w = W0[i * FH_ + j];
#pragma unroll
      for (int a = 0; a < AB; ++a) acc8[a] = fmaf(sX[a][i], w, acc8[a]);
    }
#pragma unroll
    for (int a = 0; a < AB; ++a) sH0[a][j] = fast_tanh(acc8[a]);
  }
  __syncthreads();
  if (j < FH_) {  // layer 1 (residual)
    float acc8[AB];
#pragma unroll
    for (int a = 0; a < AB; ++a) acc8[a] = B1[j];
    for (int f = 0; f < FH_; ++f) {
      float w = W1[f * FH_ + j];
#pragma unroll
      for (int a = 0; a < AB; ++a) acc8[a] = fmaf(sH0[a][f], w, acc8[a]);
    }
#pragma unroll
    for (int a = 0; a < AB; ++a) {
      float tv = fast_tanh(acc8[a]);
      sT1[a][j] = tv;
      sH1[a][j] = sH0[a][j] + tv;
    }
  }
  __syncthreads();
  if (j < FH_) {  // layer 2 (residual) + Ei dot
    float acc8[AB];
#pragma unroll
    for (int a = 0; a < AB; ++a) acc8[a] = B2[j];
    for (int f = 0; f < FH_; ++f) {
      float w = W2[f * FH_ + j];
#pragma unroll
      for (int a = 0; a < AB; ++a) acc8[a] = fmaf(sH1[a][f], w, acc8[a]);
    }
    float w3 = W3[j];
#pragma unroll
    for (int a = 0; a < AB; ++a) {
      float tv = fast_tanh(acc8[a]);
      sT2[a][j] = tv;
      atomicAdd(&sEi[a], (sH1[a][j] + tv) * w3);
    }
  }
  __syncthreads();
  if (tid < AB) {
    float ei = sEi[tid] + fb3[t] + ener_shift[t];
    out[8 + a0 + tid] = ei;            // Ei
    atomicAdd(&out[bb], ei);           // Etot
  }
  if (j < FH_) {  // g2 = W3 * (1 - t2^2)   (dEi = 1)
    float w3 = W3[j];
#pragma unroll
    for (int a = 0; a < AB; ++a) {
      float tv = sT2[a][j];
      sT2[a][j] = w3 * (1.0f - tv * tv);
    }
  }
  __syncthreads();
  if (j < FH_) {  // dh1 = W3 + g2 @ W2^T ; g1 = dh1*(1-t1^2)
    float w3 = W3[j];
    float acc8[AB];
#pragma unroll
    for (int a = 0; a < AB; ++a) acc8[a] = w3;
    for (int k = 0; k < FH_; ++k) {
      float w = W2[j * FH_ + k];
#pragma unroll
      for (int a = 0; a < AB; ++a) acc8[a] = fmaf(sT2[a][k], w, acc8[a]);
    }
#pragma unroll
    for (int a = 0; a < AB; ++a) {
      float dh1 = acc8[a];
      float tv = sT1[a][j];
      sH1[a][j] = dh1;
      sT1[a][j] = dh1 * (1.0f - tv * tv);
    }
  }
  __syncthreads();
  if (j < FH_) {  // dh0 = dh1 + g1 @ W1^T ; g0 = dh0*(1-h0^2)
    float acc8[AB];
#pragma unroll
    for (int a = 0; a < AB; ++a) acc8[a] = sH1[a][j];
    for (int k = 0; k < FH_; ++k) {
      float w = W1[j * FH_ + k];
#pragma unroll
      for (int a = 0; a < AB; ++a) acc8[a] = fmaf(sT1[a][k], w, acc8[a]);
    }
#pragma unroll
    for (int a = 0; a < AB; ++a) {
      float h0v = sH0[a][j];
      sH0[a][j] = acc8[a] * (1.0f - h0v * h0v);
    }
  }
  __syncthreads();
  // dx = g0 @ W0^T  (overwrite sX)
  for (int i = tid; i < 400; i += 256) {
    float acc8[AB];
#pragma unroll
    for (int a = 0; a < AB; ++a) acc8[a] = 0.0f;
    for (int jj = 0; jj < FH_; ++jj) {
      float w = W0[i * FH_ + jj];
#pragma unroll
      for (int a = 0; a < AB; ++a) acc8[a] = fmaf(sH0[a][jj], w, acc8[a]);
    }
#pragma unroll
    for (int a = 0; a < AB; ++a) sX[a][i] = acc8[a];
  }
  __syncthreads();
  // dacc[d][e] = sum_{f<16} dDRt[e][f]*acc[d][f] + [e<16] sum_e2 dDRt[e2][e]*acc[d][e2]
  for (int idx = tid; idx < AB * 100; idx += 256) {
    int a = idx / 100; int r = idx % 100; int d = r / 25; int e = r % 25;
    const float* A = sAcc[a];
    const float* DX = sX[a];
    float sum = 0.0f;
#pragma unroll
    for (int f = 0; f < 16; ++f) sum = fmaf(DX[e * 16 + f], A[d * 25 + f], sum);
    if (e < 16) {
#pragma unroll
      for (int e2 = 0; e2 < 25; ++e2) sum = fmaf(DX[e2 * 16 + e], A[d * 25 + e2], sum);
    }
    dacc_ws[a0 * 100 + idx] = sum;
  }
}

// K3: pure-register JVP. The allocator-attribute map from R1/R7/R8:
// waves_per_eu(min,max) -> VGPR ~ 512/(2*min) REGARDLESS of max:
//   (2,2)->88 no-spill (R1) | (4,4)->64 remat (R8) | (5,5)->48 spill (R7).
// And max is what caps HW residency: R1's 88 regs FIT 5 waves/SIMD
// (512/88=5.8) but max=2 forbade running them — that cap, not allocation,
// held every clean variant at <=3 waves/SIMD and 40% VALU duty (busy time
// is invariant 219-223us across R1/R2/R3/R8; R7 proved 96% duty possible).
// This round: (2,5) — min=2 reproduces the proven 88-reg no-spill
// allocation; max=5 lets the HW run the 5 waves those registers afford.
// Predict: VGPR~88-102, FETCH~20MB (clean), occ 37->~55-62%, VALUBusy
// 41->85-96%, dur 535->~240-300us. Falsifier: VGPR<=64 / FETCH>>20MB =>
// allocator chased max; fallback is R5-loop at GATOMS=8, default bounds.
__global__ __launch_bounds__(256) __attribute__((amdgpu_waves_per_eu(2, 5)))
void k_bwd_force(
    const float* __restrict__ dR, const int* __restrict__ neigh,
    const float* __restrict__ davg, const float* __restrict__ dstd,
    const float* __restrict__ eW0, const float* __restrict__ eb0,
    const float* __restrict__ eW1, const float* __restrict__ eb1,
    const float* __restrict__ eW2, const float* __restrict__ eb2,
    const float* __restrict__ dacc_ws, float* __restrict__ out) {
  int atom = blockIdx.x;
  int bb = atom >> 10;
  int n = atom & (N_ - 1);
  int t = (n >= 512) ? 1 : 0;
  int m = threadIdx.x;
  int p = __builtin_amdgcn_readfirstlane(t * 2 + (m >> 7));
  const float* W0 = eW0 + p * D_;
  const float* b0 = eb0 + p * D_;
  const float* W1 = eW1 + p * D_ * D_;
  const float* b1 = eb1 + p * D_;
  const float* W2 = eW2 + p * D_ * D_;
  const float* b2 = eb2 + p * D_;
  const float* dac = dacc_ws + atom * 100;  // block-uniform -> scalar loads
  int base = atom * M_ + m;
  float dx = dR[base * 3 + 0];
  float dy = dR[base * 3 + 1];
  float dz = dR[base * 3 + 2];
  int nb = neigh[base];
  Geom g = geom_core(dx, dy, dz, nb);
  float blk[4], rsv[4];
  geom_blk(g, dx, dy, dz, t, m, davg, dstd, blk, rsv);

  // ---- fused forward + d/ds (JVP) through the embedding MLP ----
  float s = blk[0];
  float h[D_], hp[D_];          // value, d/ds
#pragma unroll
  for (int e = 0; e < D_; ++e) {
    float th = fast_tanh(fmaf(s, W0[e], b0[e]));
    h[e] = th;
    hp[e] = (1.0f - th * th) * W0[e];
  }
  {  // layer 1 (residual)
    float a[D_], ap[D_];
#pragma unroll
    for (int e = 0; e < D_; ++e) { a[e] = b1[e]; ap[e] = 0.0f; }
#pragma unroll
    for (int f = 0; f < D_; ++f) {
      float hf = h[f], gf = hp[f];
#pragma unroll
      for (int e = 0; e < D_; ++e) {
        float w = W1[f * D_ + e];
        a[e] = fmaf(hf, w, a[e]);
        ap[e] = fmaf(gf, w, ap[e]);
      }
    }
#pragma unroll
    for (int e = 0; e < D_; ++e) {
      float th = fast_tanh(a[e]);
      h[e] += th;
      hp[e] = fmaf(1.0f - th * th, ap[e], hp[e]);
    }
  }
  {  // layer 2 (residual) -> h = G, hp = dG/ds
    float a[D_], ap[D_];
#pragma unroll
    for (int e = 0; e < D_; ++e) { a[e] = b2[e]; ap[e] = 0.0f; }
#pragma unroll
    for (int f = 0; f < D_; ++f) {
      float hf = h[f], gf = hp[f];
#pragma unroll
      for (int e = 0; e < D_; ++e) {
        float w = W2[f * D_ + e];
        a[e] = fmaf(hf, w, a[e]);
        ap[e] = fmaf(gf, w, ap[e]);
      }
    }
#pragma unroll
    for (int e = 0; e < D_; ++e) {
      float th = fast_tanh(a[e]);
      h[e] += th;
      hp[e] = fmaf(1.0f - th * th, ap[e], hp[e]);
    }
  }

  // ---- gradients: dE[d] = CSC*(sum_e dac[d][e]*G[e]) + [d==0] ds ----
  float ds = 0.0f, db0 = 0.0f, db1 = 0.0f, db2 = 0.0f, db3 = 0.0f;
#pragma unroll
  for (int e = 0; e < D_; ++e) {
    float d0 = dac[e], d1 = dac[25 + e], d2 = dac[50 + e], d3 = dac[75 + e];
    float gG = d0 * blk[0] + d1 * blk[1] + d2 * blk[2] + d3 * blk[3];
    ds = fmaf(gG, hp[e], ds);
    float he = h[e];
    db0 = fmaf(d0, he, db0);
    db1 = fmaf(d1, he, db1);
    db2 = fmaf(d2, he, db2);
    db3 = fmaf(d3, he, db3);
  }
  float dE0 = (db0 + ds) * CSC;
  float dE1 = db1 * CSC, dE2 = db2 * CSC, dE3 = db3 * CSC;

  // ---- fold the 4x3 geometry Jacobian directly into the force vector ----
  float dv[3] = {dx, dy, dz};
  float pre1[3] = {dx * g.inr2, dy * g.inr2, dz * g.inr2};
  float ci = g.dvv * g.inr;
  float com[3];
#pragma unroll
  for (int c = 0; c < 3; ++c) com[c] = ci * dv[c];
  float iv = g.inr3 * g.vv;
  float pc[3];
  float f0 = dE0 * rsv[0];
#pragma unroll
  for (int c = 0; c < 3; ++c) pc[c] = f0 * (dv[c] * iv - g.inr * com[c]);
  float dEr[3] = {dE1, dE2, dE3};
#pragma unroll
  for (int r = 0; r < 3; ++r) {
    float fr = dEr[r] * rsv[1 + r];
#pragma unroll
    for (int c = 0; c < 3; ++c) {
      float outer = 2.0f * dv[r] * dv[c] * g.inr4 - ((r == c) ? g.inr2 : 0.0f);
      pc[c] = fmaf(fr, outer * g.vv - pre1[r] * com[c], pc[c]);
    }
  }
  float px = pc[0] * g.mf, py = pc[1] * g.mf, pz = pc[2] * g.mf;

  if (nb > 0) {  // scatter to neighbor j = nb-1
    int jn = nb - 1;
    int fi = 8 + NATOM + (bb * N_ + jn) * 3;
    atomicAdd(&out[fi + 0], px);
    atomicAdd(&out[fi + 1], py);
    atomicAdd(&out[fi + 2], pz);
  }
  // F_self: 64-lane shuffle reduce, one atomic per wave per component
#pragma unroll
  for (int i = 1; i < 64; i <<= 1) {
    px += __shfl_xor(px, i);
    py += __shfl_xor(py, i);
    pz += __shfl_xor(pz, i);
  }
  if ((m & 63) == 0) {
    int fi = 8 + NATOM + atom * 3;
    atomicAdd(&out[fi + 0], -px);
    atomicAdd(&out[fi + 1], -py);
    atomicAdd(&out[fi + 2], -pz);
  }
}

}  // namespace

extern "C" void kernel_launch(void* const* d_in, const int* in_sizes, int n_in,
                              void* d_out, int out_size, void* d_ws, size_t ws_size,
                              hipStream_t stream) {
  (void)in_sizes; (void)n_in; (void)ws_size;
  const float* image_dR   = (const float*)d_in[0];
  const int*   list_neigh = (const int*)d_in[1];
  const float* davg       = (const float*)d_in[2];
  const float* dstd       = (const float*)d_in[3];
  const float* eW0        = (const float*)d_in[4];
  const float* eb0        = (const float*)d_in[5];
  const float* eW1        = (const float*)d_in[6];
  const float* eb1        = (const float*)d_in[7];
  const float* eW2        = (const float*)d_in[8];
  const float* eb2        = (const float*)d_in[9];
  const float* fW0        = (const float*)d_in[10];
  const float* fb0        = (const float*)d_in[11];
  const float* fW1        = (const float*)d_in[12];
  const float* fb1        = (const float*)d_in[13];
  const float* fW2        = (const float*)d_in[14];
  const float* fb2        = (const float*)d_in[15];
  const float* fW3        = (const float*)d_in[16];
  const float* fb3        = (const float*)d_in[17];
  const float* ener_shift = (const float*)d_in[18];
  float* out = (float*)d_out;
  float* acc_ws  = (float*)d_ws;                  // 8192*100 floats
  float* dacc_ws = acc_ws + NATOM * 100;          // 8192*100 floats

  hipMemsetAsync(d_out, 0, (size_t)out_size * sizeof(float), stream);
  k_embed_acc<<<NATOM, 256, 0, stream>>>(image_dR, list_neigh, davg, dstd,
                                         eW0, eb0, eW1, eb1, eW2, eb2, acc_ws);
  k_fit<<<NATOM / 8, 256, 0, stream>>>(acc_ws, fW0, fb0, fW1, fb1, fW2, fb2,
                                       fW3, fb3, ener_shift, dacc_ws, out);
  k_bwd_force<<<NATOM, 256, 0, stream>>>(image_dR, list_neigh, davg, dstd,
                                         eW0, eb0, eW1, eb1, eW2, eb2,
                                         dacc_ws, out);
}

// Round 11
// 943.994 us; speedup vs baseline: 3.4029x; 1.0046x over previous
//
#include <hip/hip_runtime.h>

#define DEV __device__ __forceinline__

namespace {

constexpr int B_ = 8;
constexpr int N_ = 1024;
constexpr int M_ = 256;
constexpr int D_ = 25;
constexpr int FH_ = 240;
constexpr int NATOM = B_ * N_;          // 8192
constexpr float CSC = 1.0f / 256.0f;    // 4/(NN*NTYPES*4)
constexpr int WROW = 28;                // padded row (112B, 16B-aligned)
constexpr int WPAIR = 4 * WROW + 2 * D_ * WROW;  // 112 + 1400 = 1512 floats

DEV float fast_tanh(float x) {
  float ax = fabsf(x);
  float e = __expf(-2.0f * ax);
  float r = (1.0f - e) * __builtin_amdgcn_rcpf(1.0f + e);
  return copysignf(r, x);
}

// Scalar geometry pieces shared by descriptor and Jacobian.
struct Geom {
  float mf, inr, inr2, inr4, inr3, vv, dvv;
};

DEV Geom geom_core(float dx, float dy, float dz, int nb) {
  Geom g;
  g.mf = (nb > 0) ? 1.0f : 0.0f;
  float dr2 = dx * dx + dy * dy + dz * dz;
  float safe = (nb > 0) ? dr2 : 1.0f;
  float rs = __builtin_amdgcn_rsqf(safe);   // 1/sqrt(safe)
  float rij = safe * rs;                    // sqrt(safe)
  g.inr = g.mf * rs;
  float x = rij * g.mf;
  g.inr2 = g.inr * g.inr;
  g.inr4 = g.inr2 * g.inr2;
  g.inr3 = g.inr4 * x;
  float u = (x - 5.8f) * 5.0f;              // (x-RMIN)/(RMAX-RMIN)
  float uu = u * u;
  float A = -6.0f * uu + 15.0f * u - 10.0f;
  float poly = uu * u * A + 1.0f;
  float dpoly = (3.0f * uu * A + uu * u * (-12.0f * u + 15.0f)) * 5.0f;
  bool mid = (x >= 5.8f) && (x < 6.0f);
  g.vv = ((x < 5.8f) ? 1.0f : (mid ? poly : 0.0f)) * g.mf;
  g.dvv = (mid ? dpoly : 0.0f) * g.mf;
  return g;
}

// Normalized descriptor channels blk[4]; also returns 1/dstd per channel.
DEV void geom_blk(const Geom& g, float dx, float dy, float dz, int t, int m,
                  const float* __restrict__ davg, const float* __restrict__ dstd,
                  float* __restrict__ blk, float* __restrict__ rsv) {
  int bidx = (t * M_ + m) * 4;
  float4 av = *(const float4*)(davg + bidx);
  float4 sv = *(const float4*)(dstd + bidx);
  float pre[4] = {g.inr, dx * g.inr2, dy * g.inr2, dz * g.inr2};
  float avf[4] = {av.x, av.y, av.z, av.w};
  float svf[4] = {sv.x, sv.y, sv.z, sv.w};
#pragma unroll
  for (int d = 0; d < 4; ++d) {
    rsv[d] = __builtin_amdgcn_rcpf(svf[d]);
    blk[d] = (pre[d] * g.vv - avf[d]) * rsv[d];
  }
}

// Load one padded 28-float LDS row into registers (static element indices).
DEV void load_wrow(const float* __restrict__ wr, float* __restrict__ wrow) {
#pragma unroll
  for (int k = 0; k < 7; ++k) {
    float4 qv = ((const float4*)wr)[k];
    wrow[4 * k + 0] = qv.x;
    wrow[4 * k + 1] = qv.y;
    wrow[4 * k + 2] = qv.z;
    wrow[4 * k + 3] = qv.w;
  }
}

// Stage both (t,*) weight pairs into LDS, 16B-aligned segments:
// [0:28] W0 | [28:56] b0 | [56:84] b1 | [84:112] b2 |
// [112:112+700] W1 (f-major, row f at f*28) | [812:1512] W2 (f-major).
DEV void stage_weights(int tid, int t,
                       const float* __restrict__ eW0, const float* __restrict__ eb0,
                       const float* __restrict__ eW1, const float* __restrict__ eb1,
                       const float* __restrict__ eW2, const float* __restrict__ eb2,
                       float* __restrict__ sW) {
  for (int idx = tid; idx < 2 * WPAIR; idx += 256) {
    int pl = idx / WPAIR;
    int r = idx - pl * WPAIR;
    int pp = t * 2 + pl;
    float v = 0.0f;
    if (r < 28) { if (r < 25) v = eW0[pp * 25 + r]; }
    else if (r < 56) { int e = r - 28; if (e < 25) v = eb0[pp * 25 + e]; }
    else if (r < 84) { int e = r - 56; if (e < 25) v = eb1[pp * 25 + e]; }
    else if (r < 112) { int e = r - 84; if (e < 25) v = eb2[pp * 25 + e]; }
    else if (r < 112 + D_ * WROW) {
      int rr = r - 112; int f = rr / WROW, e = rr - f * WROW;
      if (e < 25) v = eW1[pp * 625 + f * 25 + e];
    } else {
      int rr = r - (112 + D_ * WROW); int f = rr / WROW, e = rr - f * WROW;
      if (e < 25) v = eW2[pp * 625 + f * 25 + e];
    }
    sW[idx] = v;
  }
}

// K1: per atom (block), per neighbor (thread): geometry + lean embedding fwd,
// then acc[4][25] = CSC * sum_m blk[m][d] * G[m][e] via LDS reduction.
// (Untouched — control.)
__global__ __launch_bounds__(256) void k_embed_acc(
    const float* __restrict__ dR, const int* __restrict__ neigh,
    const float* __restrict__ davg, const float* __restrict__ dstd,
    const float* __restrict__ eW0, const float* __restrict__ eb0,
    const float* __restrict__ eW1, const float* __restrict__ eb1,
    const float* __restrict__ eW2, const float* __restrict__ eb2,
    float* __restrict__ acc_ws) {
  __shared__ float sG[M_ * D_];
  __shared__ float4 sBlk[M_];
  int atom = blockIdx.x;
  int n = atom & (N_ - 1);
  int t = (n >= 512) ? 1 : 0;
  int m = threadIdx.x;
  int p = __builtin_amdgcn_readfirstlane(t * 2 + (m >> 7));
  const float* W0 = eW0 + p * D_;
  const float* b0 = eb0 + p * D_;
  const float* W1 = eW1 + p * D_ * D_;
  const float* b1 = eb1 + p * D_;
  const float* W2 = eW2 + p * D_ * D_;
  const float* b2 = eb2 + p * D_;
  int base = atom * M_ + m;
  float dx = dR[base * 3 + 0];
  float dy = dR[base * 3 + 1];
  float dz = dR[base * 3 + 2];
  int nb = neigh[base];
  Geom g = geom_core(dx, dy, dz, nb);
  float blk[4], rsv[4];
  geom_blk(g, dx, dy, dz, t, m, davg, dstd, blk, rsv);
  float s = blk[0];
  float h[D_], a[D_];
#pragma unroll
  for (int e = 0; e < D_; ++e) h[e] = fast_tanh(fmaf(s, W0[e], b0[e]));
#pragma unroll
  for (int e = 0; e < D_; ++e) a[e] = b1[e];
#pragma unroll
  for (int f = 0; f < D_; ++f) {
    float hf = h[f];
#pragma unroll
    for (int e = 0; e < D_; ++e) a[e] = fmaf(hf, W1[f * D_ + e], a[e]);
  }
#pragma unroll
  for (int e = 0; e < D_; ++e) h[e] += fast_tanh(a[e]);   // h1
#pragma unroll
  for (int e = 0; e < D_; ++e) a[e] = b2[e];
#pragma unroll
  for (int f = 0; f < D_; ++f) {
    float hf = h[f];
#pragma unroll
    for (int e = 0; e < D_; ++e) a[e] = fmaf(hf, W2[f * D_ + e], a[e]);
  }
#pragma unroll
  for (int e = 0; e < D_; ++e) sG[m * D_ + e] = h[e] + fast_tanh(a[e]);  // G
  sBlk[m] = make_float4(blk[0], blk[1], blk[2], blk[3]);
  __syncthreads();
  if (threadIdx.x < 100) {
    int d = threadIdx.x & 3;
    int e = threadIdx.x >> 2;
    const float* sb = (const float*)sBlk;
    float s0 = 0.0f, s1 = 0.0f, s2 = 0.0f, s3 = 0.0f;
    for (int mm = 0; mm < M_; mm += 4) {
      s0 = fmaf(sb[(mm + 0) * 4 + d], sG[(mm + 0) * D_ + e], s0);
      s1 = fmaf(sb[(mm + 1) * 4 + d], sG[(mm + 1) * D_ + e], s1);
      s2 = fmaf(sb[(mm + 2) * 4 + d], sG[(mm + 2) * D_ + e], s2);
      s3 = fmaf(sb[(mm + 3) * 4 + d], sG[(mm + 3) * D_ + e], s3);
    }
    acc_ws[atom * 100 + d * D_ + e] = ((s0 + s1) + (s2 + s3)) * CSC;
  }
}

// K2: 8 atoms per block. All activation arrays transposed to [FH][AB] so
// each inner-loop access is 2x broadcast ds_read_b128 (32B contiguous,
// wave-uniform) instead of 8 scattered ds_read_b32 — ~4x fewer LDS ops.
__global__ __launch_bounds__(256) void k_fit(
    const float* __restrict__ acc_ws,
    const float* __restrict__ fW0, const float* __restrict__ fb0,
    const float* __restrict__ fW1, const float* __restrict__ fb1,
    const float* __restrict__ fW2, const float* __restrict__ fb2,
    const float* __restrict__ fW3, const float* __restrict__ fb3,
    const float* __restrict__ ener_shift,
    float* __restrict__ dacc_ws, float* __restrict__ out) {
  constexpr int AB = 8;
  __shared__ float sAcc[AB][100];
  __shared__ __align__(16) float sX[400 * AB];   // [i][a]
  __shared__ __align__(16) float sH0[FH_ * AB];  // [j][a] h0, then g0
  __shared__ __align__(16) float sT1[FH_ * AB];  // tanh1, then g1
  __shared__ __align__(16) float sH1[FH_ * AB];  // h1, then dh1
  __shared__ __align__(16) float sT2[FH_ * AB];  // tanh2, then g2
  __shared__ float sEi[AB];
  int a0 = blockIdx.x * AB;
  int bb = a0 >> 10;
  int n0 = a0 & (N_ - 1);
  int t = (n0 >= 512) ? 1 : 0;
  int tid = threadIdx.x;
  for (int idx = tid; idx < AB * 100; idx += 256)
    ((float*)sAcc)[idx] = acc_ws[a0 * 100 + idx];
  if (tid < AB) sEi[tid] = 0.0f;
  __syncthreads();
  // DRt[e][f] = sum_d acc[d][e]*acc[d][f], f<16  -> sX[r][a]
  for (int idx = tid; idx < AB * 400; idx += 256) {
    int a = idx / 400; int r = idx % 400; int e = r >> 4; int f = r & 15;
    const float* A = sAcc[a];
    sX[r * AB + a] = A[e] * A[f] + A[25 + e] * A[25 + f] +
                     A[50 + e] * A[50 + f] + A[75 + e] * A[75 + f];
  }
  __syncthreads();
  const float* W0 = fW0 + t * 400 * FH_;
  const float* W1 = fW1 + t * FH_ * FH_;
  const float* W2 = fW2 + t * FH_ * FH_;
  const float* B0 = fb0 + t * FH_;
  const float* B1 = fb1 + t * FH_;
  const float* B2 = fb2 + t * FH_;
  const float* W3 = fW3 + t * FH_;
  int j = tid;
  if (j < FH_) {  // layer 0: 400 -> 240
    float acc8[AB];
#pragma unroll
    for (int a = 0; a < AB; ++a) acc8[a] = B0[j];
    for (int i = 0; i < 400; ++i) {
      float w = W0[i * FH_ + j];
      const float4* xr = (const float4*)(sX + i * AB);
      float4 x0 = xr[0], x1 = xr[1];
      acc8[0] = fmaf(x0.x, w, acc8[0]); acc8[1] = fmaf(x0.y, w, acc8[1]);
      acc8[2] = fmaf(x0.z, w, acc8[2]); acc8[3] = fmaf(x0.w, w, acc8[3]);
      acc8[4] = fmaf(x1.x, w, acc8[4]); acc8[5] = fmaf(x1.y, w, acc8[5]);
      acc8[6] = fmaf(x1.z, w, acc8[6]); acc8[7] = fmaf(x1.w, w, acc8[7]);
    }
    float4* h0 = (float4*)(sH0 + j * AB);
    h0[0] = make_float4(fast_tanh(acc8[0]), fast_tanh(acc8[1]),
                        fast_tanh(acc8[2]), fast_tanh(acc8[3]));
    h0[1] = make_float4(fast_tanh(acc8[4]), fast_tanh(acc8[5]),
                        fast_tanh(acc8[6]), fast_tanh(acc8[7]));
  }
  __syncthreads();
  if (j < FH_) {  // layer 1 (residual)
    float acc8[AB];
#pragma unroll
    for (int a = 0; a < AB; ++a) acc8[a] = B1[j];
    for (int f = 0; f < FH_; ++f) {
      float w = W1[f * FH_ + j];
      const float4* hr = (const float4*)(sH0 + f * AB);
      float4 h0a = hr[0], h0b = hr[1];
      acc8[0] = fmaf(h0a.x, w, acc8[0]); acc8[1] = fmaf(h0a.y, w, acc8[1]);
      acc8[2] = fmaf(h0a.z, w, acc8[2]); acc8[3] = fmaf(h0a.w, w, acc8[3]);
      acc8[4] = fmaf(h0b.x, w, acc8[4]); acc8[5] = fmaf(h0b.y, w, acc8[5]);
      acc8[6] = fmaf(h0b.z, w, acc8[6]); acc8[7] = fmaf(h0b.w, w, acc8[7]);
    }
#pragma unroll
    for (int a = 0; a < AB; ++a) {
      float tv = fast_tanh(acc8[a]);
      sT1[j * AB + a] = tv;
      sH1[j * AB + a] = sH0[j * AB + a] + tv;
    }
  }
  __syncthreads();
  if (j < FH_) {  // layer 2 (residual) + Ei dot
    float acc8[AB];
#pragma unroll
    for (int a = 0; a < AB; ++a) acc8[a] = B2[j];
    for (int f = 0; f < FH_; ++f) {
      float w = W2[f * FH_ + j];
      const float4* hr = (const float4*)(sH1 + f * AB);
      float4 h1a = hr[0], h1b = hr[1];
      acc8[0] = fmaf(h1a.x, w, acc8[0]); acc8[1] = fmaf(h1a.y, w, acc8[1]);
      acc8[2] = fmaf(h1a.z, w, acc8[2]); acc8[3] = fmaf(h1a.w, w, acc8[3]);
      acc8[4] = fmaf(h1b.x, w, acc8[4]); acc8[5] = fmaf(h1b.y, w, acc8[5]);
      acc8[6] = fmaf(h1b.z, w, acc8[6]); acc8[7] = fmaf(h1b.w, w, acc8[7]);
    }
    float w3 = W3[j];
#pragma unroll
    for (int a = 0; a < AB; ++a) {
      float tv = fast_tanh(acc8[a]);
      sT2[j * AB + a] = tv;
      atomicAdd(&sEi[a], (sH1[j * AB + a] + tv) * w3);
    }
  }
  __syncthreads();
  if (tid < AB) {
    float ei = sEi[tid] + fb3[t] + ener_shift[t];
    out[8 + a0 + tid] = ei;            // Ei
    atomicAdd(&out[bb], ei);           // Etot
  }
  if (j < FH_) {  // g2 = W3 * (1 - t2^2)   (dEi = 1)
    float w3 = W3[j];
#pragma unroll
    for (int a = 0; a < AB; ++a) {
      float tv = sT2[j * AB + a];
      sT2[j * AB + a] = w3 * (1.0f - tv * tv);
    }
  }
  __syncthreads();
  if (j < FH_) {  // dh1 = W3 + g2 @ W2^T ; g1 = dh1*(1-t1^2)
    float w3 = W3[j];
    float acc8[AB];
#pragma unroll
    for (int a = 0; a < AB; ++a) acc8[a] = w3;
    for (int k = 0; k < FH_; ++k) {
      float w = W2[j * FH_ + k];
      const float4* gr = (const float4*)(sT2 + k * AB);
      float4 g2a = gr[0], g2b = gr[1];
      acc8[0] = fmaf(g2a.x, w, acc8[0]); acc8[1] = fmaf(g2a.y, w, acc8[1]);
      acc8[2] = fmaf(g2a.z, w, acc8[2]); acc8[3] = fmaf(g2a.w, w, acc8[3]);
      acc8[4] = fmaf(g2b.x, w, acc8[4]); acc8[5] = fmaf(g2b.y, w, acc8[5]);
      acc8[6] = fmaf(g2b.z, w, acc8[6]); acc8[7] = fmaf(g2b.w, w, acc8[7]);
    }
#pragma unroll
    for (int a = 0; a < AB; ++a) {
      float dh1 = acc8[a];
      float tv = sT1[j * AB + a];
      sH1[j * AB + a] = dh1;
      sT1[j * AB + a] = dh1 * (1.0f - tv * tv);
    }
  }
  __syncthreads();
  if (j < FH_) {  // dh0 = dh1 + g1 @ W1^T ; g0 = dh0*(1-h0^2)
    float acc8[AB];
#pragma unroll
    for (int a = 0; a < AB; ++a) acc8[a] = sH1[j * AB + a];
    for (int k = 0; k < FH_; ++k) {
      float w = W1[j * FH_ + k];
      const float4* gr = (const float4*)(sT1 + k * AB);
      float4 g1a = gr[0], g1b = gr[1];
      acc8[0] = fmaf(g1a.x, w, acc8[0]); acc8[1] = fmaf(g1a.y, w, acc8[1]);
      acc8[2] = fmaf(g1a.z, w, acc8[2]); acc8[3] = fmaf(g1a.w, w, acc8[3]);
      acc8[4] = fmaf(g1b.x, w, acc8[4]); acc8[5] = fmaf(g1b.y, w, acc8[5]);
      acc8[6] = fmaf(g1b.z, w, acc8[6]); acc8[7] = fmaf(g1b.w, w, acc8[7]);
    }
#pragma unroll
    for (int a = 0; a < AB; ++a) {
      float h0v = sH0[j * AB + a];
      sH0[j * AB + a] = acc8[a] * (1.0f - h0v * h0v);
    }
  }
  __syncthreads();
  // dx = g0 @ W0^T  (overwrite sX)
  for (int i = tid; i < 400; i += 256) {
    float acc8[AB];
#pragma unroll
    for (int a = 0; a < AB; ++a) acc8[a] = 0.0f;
    for (int jj = 0; jj < FH_; ++jj) {
      float w = W0[i * FH_ + jj];
      const float4* gr = (const float4*)(sH0 + jj * AB);
      float4 g0a = gr[0], g0b = gr[1];
      acc8[0] = fmaf(g0a.x, w, acc8[0]); acc8[1] = fmaf(g0a.y, w, acc8[1]);
      acc8[2] = fmaf(g0a.z, w, acc8[2]); acc8[3] = fmaf(g0a.w, w, acc8[3]);
      acc8[4] = fmaf(g0b.x, w, acc8[4]); acc8[5] = fmaf(g0b.y, w, acc8[5]);
      acc8[6] = fmaf(g0b.z, w, acc8[6]); acc8[7] = fmaf(g0b.w, w, acc8[7]);
    }
    float4* xw = (float4*)(sX + i * AB);
    xw[0] = make_float4(acc8[0], acc8[1], acc8[2], acc8[3]);
    xw[1] = make_float4(acc8[4], acc8[5], acc8[6], acc8[7]);
  }
  __syncthreads();
  // dacc[d][e] = sum_{f<16} dDRt[e][f]*acc[d][f] + [e<16] sum_e2 dDRt[e2][e]*acc[d][e2]
  for (int idx = tid; idx < AB * 100; idx += 256) {
    int a = idx / 100; int r = idx % 100; int d = r / 25; int e = r % 25;
    const float* A = sAcc[a];
    float sum = 0.0f;
#pragma unroll
    for (int f = 0; f < 16; ++f)
      sum = fmaf(sX[(e * 16 + f) * AB + a], A[d * 25 + f], sum);
    if (e < 16) {
#pragma unroll
      for (int e2 = 0; e2 < 25; ++e2)
        sum = fmaf(sX[(e2 * 16 + e) * AB + a], A[d * 25 + e2], sum);
    }
    dacc_ws[a0 * 100 + idx] = sum;
  }
}

// K3: pure-register JVP, unrolled, weights+dac staged in LDS.
// Theory (R1-R9): clean K3 VALU-issue time invariant ~220us, duty pinned
// 40-46% independent of occupancy -> the ~170 s_load batches/wave saturate
// the per-CU scalar cache port shared by 4 SIMDs. Weights move to the
// vector path: broadcast ds_read_b128 at static offsets; dac to LDS too.
// waves_per_eu(2,8): min=2 = proven-clean register budget, max=8 = open cap.
__global__ __launch_bounds__(256) __attribute__((amdgpu_waves_per_eu(2, 8)))
void k_bwd_force(
    const float* __restrict__ dR, const int* __restrict__ neigh,
    const float* __restrict__ davg, const float* __restrict__ dstd,
    const float* __restrict__ eW0, const float* __restrict__ eb0,
    const float* __restrict__ eW1, const float* __restrict__ eb1,
    const float* __restrict__ eW2, const float* __restrict__ eb2,
    const float* __restrict__ dacc_ws, float* __restrict__ out) {
  __shared__ __align__(16) float sW[2 * WPAIR];  // 12.1KB
  __shared__ float sDac[100];
  int atom = blockIdx.x;
  int bb = atom >> 10;
  int n = atom & (N_ - 1);
  int t = (n >= 512) ? 1 : 0;
  int m = threadIdx.x;
  stage_weights(m, t, eW0, eb0, eW1, eb1, eW2, eb2, sW);
  for (int idx = m; idx < 100; idx += 256) sDac[idx] = dacc_ws[atom * 100 + idx];
  __syncthreads();
  const float* wp = sW + (m >> 7) * WPAIR;  // wave-uniform
  int base = atom * M_ + m;
  float dx = dR[base * 3 + 0];
  float dy = dR[base * 3 + 1];
  float dz = dR[base * 3 + 2];
  int nb = neigh[base];
  Geom g = geom_core(dx, dy, dz, nb);
  float blk[4], rsv[4];
  geom_blk(g, dx, dy, dz, t, m, davg, dstd, blk, rsv);

  // ---- fused forward + d/ds (JVP); weights via LDS broadcast reads ----
  float s = blk[0];
  float h[D_], hp[D_];
  {
    float w0r[WROW], b0r[WROW];
    load_wrow(wp, w0r);
    load_wrow(wp + WROW, b0r);
#pragma unroll
    for (int e = 0; e < D_; ++e) {
      float th = fast_tanh(fmaf(s, w0r[e], b0r[e]));
      h[e] = th;
      hp[e] = (1.0f - th * th) * w0r[e];
    }
  }
  {  // layer 1 (residual)
    float a[D_], ap[D_];
    {
      float b1r[WROW];
      load_wrow(wp + 2 * WROW, b1r);
#pragma unroll
      for (int e = 0; e < D_; ++e) { a[e] = b1r[e]; ap[e] = 0.0f; }
    }
#pragma unroll
    for (int f = 0; f < D_; ++f) {
      float wrow[WROW];
      load_wrow(wp + 4 * WROW + f * WROW, wrow);
      float hf = h[f], gf = hp[f];
#pragma unroll
      for (int e = 0; e < D_; ++e) {
        a[e] = fmaf(hf, wrow[e], a[e]);
        ap[e] = fmaf(gf, wrow[e], ap[e]);
      }
    }
#pragma unroll
    for (int e = 0; e < D_; ++e) {
      float th = fast_tanh(a[e]);
      h[e] += th;
      hp[e] = fmaf(1.0f - th * th, ap[e], hp[e]);
    }
  }
  {  // layer 2 (residual) -> h = G, hp = dG/ds
    float a[D_], ap[D_];
    {
      float b2r[WROW];
      load_wrow(wp + 3 * WROW, b2r);
#pragma unroll
      for (int e = 0; e < D_; ++e) { a[e] = b2r[e]; ap[e] = 0.0f; }
    }
#pragma unroll
    for (int f = 0; f < D_; ++f) {
      float wrow[WROW];
      load_wrow(wp + (4 + D_) * WROW + f * WROW, wrow);
      float hf = h[f], gf = hp[f];
#pragma unroll
      for (int e = 0; e < D_; ++e) {
        a[e] = fmaf(hf, wrow[e], a[e]);
        ap[e] = fmaf(gf, wrow[e], ap[e]);
      }
    }
#pragma unroll
    for (int e = 0; e < D_; ++e) {
      float th = fast_tanh(a[e]);
      h[e] += th;
      hp[e] = fmaf(1.0f - th * th, ap[e], hp[e]);
    }
  }

  // ---- gradients: dE[d] = CSC*(sum_e dac[d][e]*G[e]) + [d==0] ds ----
  float ds = 0.0f, db0 = 0.0f, db1 = 0.0f, db2 = 0.0f, db3 = 0.0f;
#pragma unroll
  for (int e = 0; e < D_; ++e) {
    float d0 = sDac[e], d1 = sDac[25 + e], d2 = sDac[50 + e], d3 = sDac[75 + e];
    float gG = d0 * blk[0] + d1 * blk[1] + d2 * blk[2] + d3 * blk[3];
    ds = fmaf(gG, hp[e], ds);
    float he = h[e];
    db0 = fmaf(d0, he, db0);
    db1 = fmaf(d1, he, db1);
    db2 = fmaf(d2, he, db2);
    db3 = fmaf(d3, he, db3);
  }
  float dE0 = (db0 + ds) * CSC;
  float dE1 = db1 * CSC, dE2 = db2 * CSC, dE3 = db3 * CSC;

  // ---- fold the 4x3 geometry Jacobian directly into the force vector ----
  float dv[3] = {dx, dy, dz};
  float pre1[3] = {dx * g.inr2, dy * g.inr2, dz * g.inr2};
  float ci = g.dvv * g.inr;
  float com[3];
#pragma unroll
  for (int c = 0; c < 3; ++c) com[c] = ci * dv[c];
  float iv = g.inr3 * g.vv;
  float pc[3];
  float f0 = dE0 * rsv[0];
#pragma unroll
  for (int c = 0; c < 3; ++c) pc[c] = f0 * (dv[c] * iv - g.inr * com[c]);
  float dEr[3] = {dE1, dE2, dE3};
#pragma unroll
  for (int r = 0; r < 3; ++r) {
    float fr = dEr[r] * rsv[1 + r];
#pragma unroll
    for (int c = 0; c < 3; ++c) {
      float outer = 2.0f * dv[r] * dv[c] * g.inr4 - ((r == c) ? g.inr2 : 0.0f);
      pc[c] = fmaf(fr, outer * g.vv - pre1[r] * com[c], pc[c]);
    }
  }
  float px = pc[0] * g.mf, py = pc[1] * g.mf, pz = pc[2] * g.mf;

  if (nb > 0) {  // scatter to neighbor j = nb-1
    int jn = nb - 1;
    int fi = 8 + NATOM + (bb * N_ + jn) * 3;
    atomicAdd(&out[fi + 0], px);
    atomicAdd(&out[fi + 1], py);
    atomicAdd(&out[fi + 2], pz);
  }
  // F_self: 64-lane shuffle reduce, one atomic per wave per component
#pragma unroll
  for (int i = 1; i < 64; i <<= 1) {
    px += __shfl_xor(px, i);
    py += __shfl_xor(py, i);
    pz += __shfl_xor(pz, i);
  }
  if ((m & 63) == 0) {
    int fi = 8 + NATOM + atom * 3;
    atomicAdd(&out[fi + 0], -px);
    atomicAdd(&out[fi + 1], -py);
    atomicAdd(&out[fi + 2], -pz);
  }
}

}  // namespace

extern "C" void kernel_launch(void* const* d_in, const int* in_sizes, int n_in,
                              void* d_out, int out_size, void* d_ws, size_t ws_size,
                              hipStream_t stream) {
  (void)in_sizes; (void)n_in; (void)ws_size;
  const float* image_dR   = (const float*)d_in[0];
  const int*   list_neigh = (const int*)d_in[1];
  const float* davg       = (const float*)d_in[2];
  const float* dstd       = (const float*)d_in[3];
  const float* eW0        = (const float*)d_in[4];
  const float* eb0        = (const float*)d_in[5];
  const float* eW1        = (const float*)d_in[6];
  const float* eb1        = (const float*)d_in[7];
  const float* eW2        = (const float*)d_in[8];
  const float* eb2        = (const float*)d_in[9];
  const float* fW0        = (const float*)d_in[10];
  const float* fb0        = (const float*)d_in[11];
  const float* fW1        = (const float*)d_in[12];
  const float* fb1        = (const float*)d_in[13];
  const float* fW2        = (const float*)d_in[14];
  const float* fb2        = (const float*)d_in[15];
  const float* fW3        = (const float*)d_in[16];
  const float* fb3        = (const float*)d_in[17];
  const float* ener_shift = (const float*)d_in[18];
  float* out = (float*)d_out;
  float* acc_ws  = (float*)d_ws;                  // 8192*100 floats
  float* dacc_ws = acc_ws + NATOM * 100;          // 8192*100 floats

  hipMemsetAsync(d_out, 0, (size_t)out_size * sizeof(float), stream);
  k_embed_acc<<<NATOM, 256, 0, stream>>>(image_dR, list_neigh, davg, dstd,
                                         eW0, eb0, eW1, eb1, eW2, eb2, acc_ws);
  k_fit<<<NATOM / 8, 256, 0, stream>>>(acc_ws, fW0, fb0, fW1, fb1, fW2, fb2,
                                       fW3, fb3, ener_shift, dacc_ws, out);
  k_bwd_force<<<NATOM, 256, 0, stream>>>(image_dR, list_neigh, davg, dstd,
                                         eW0, eb0, eW1, eb1, eW2, eb2,
                                         dacc_ws, out);
}